// Round 6
// baseline (1802.418 us; speedup 1.0000x reference)
//
#include <hip/hip_runtime.h>

#define N_NODES 100000
#define N_EDGES 1600000          // == 6250 * 256 exactly
#define IN_F 128
#define HID_F 64
#define CLS_F 32
#define NB_SCAN ((N_NODES + 255) / 256)   // 391
#define NGRP 8
#define GRP_SZ (N_NODES / NGRP)           // 12500
#define SUBCAP 28000             // per (bucket,writer) capacity; mean 25000, sigma~156

// ---------------------------------------------------------------------------
// CSR build v3:
//   bucket (1 pass, wave-aggregated, XCD-local cursors & write regions)
//   -> count (bucket-local reads, XCD-local atomics)
//   -> block scan -> parallel top scan -> add base
//   -> fill (bucket-local reads, XCD-local csr regions -> full-line writebacks)
// ---------------------------------------------------------------------------

__global__ __launch_bounds__(256) void init_kernel(int* __restrict__ cnt,
                                                   int* __restrict__ scur) {
    int n = blockIdx.x * 256 + threadIdx.x;
    if (n < N_NODES) cnt[n] = 0;
    if (n < 64) scur[n] = 0;
}

// Phase A: each edge once. bucket b = dst/GRP_SZ, writer group w = blockIdx&7.
// Wave-aggregated append to bkt[(b*8+w)] sub-array; packed (dstLocal<<17)|src.
__global__ __launch_bounds__(256) void bucket_kernel(const int* __restrict__ src,
                                                     const int* __restrict__ dst,
                                                     int* __restrict__ scur,
                                                     unsigned* __restrict__ bkt) {
    int e = blockIdx.x * 256 + threadIdx.x;   // grid covers exactly N_EDGES
    int w = blockIdx.x & 7;
    int lane = threadIdx.x & 63;
    int d = dst[e], s = src[e];
    int g = d / GRP_SZ;                        // 0..7
    unsigned pk = ((unsigned)(d - g * GRP_SZ) << 17) | (unsigned)s;
#pragma unroll
    for (int b = 0; b < 8; b++) {
        unsigned long long m = __ballot(g == b);
        if (m) {
            int cntm = __popcll(m);
            int leader = __ffsll(m) - 1;
            int base = 0;
            if (lane == leader) base = atomicAdd(&scur[b * 8 + w], cntm);
            base = __shfl(base, leader);
            if (g == b) {
                int rank = __popcll(m & ((1ull << lane) - 1));
                bkt[(size_t)(b * 8 + w) * SUBCAP + base + rank] = pk;
            }
        }
    }
}

// count: group g (blockIdx&7 -> XCD g) histograms its bucket's sub-arrays
__global__ __launch_bounds__(256) void count_kernel(const int* __restrict__ scur,
                                                    const unsigned* __restrict__ bkt,
                                                    int* __restrict__ cnt) {
    int g = blockIdx.x & 7;
    int chunk = blockIdx.x >> 3;
    int stride = (gridDim.x >> 3) * 256;
    int base = g * GRP_SZ;
    for (int w = 0; w < 8; w++) {
        int sub = g * 8 + w;
        int nE = scur[sub];
        const unsigned* p = bkt + (size_t)sub * SUBCAP;
        for (int i = chunk * 256 + threadIdx.x; i < nE; i += stride) {
            atomicAdd(&cnt[base + (int)(p[i] >> 17)], 1);
        }
    }
}

// per-256-block exclusive scan of cnt -> off (local), block total -> bsum,
// dinv = rsqrt(cnt+1)
__global__ __launch_bounds__(256) void scan_block_kernel(const int* __restrict__ cnt,
                                                         int* __restrict__ off,
                                                         int* __restrict__ bsum,
                                                         float* __restrict__ dinv) {
    __shared__ int wt[4];
    int t = threadIdx.x;
    int n = blockIdx.x * 256 + t;
    int lane = t & 63, w = t >> 6;
    int c = (n < N_NODES) ? cnt[n] : 0;
    if (n < N_NODES) dinv[n] = rsqrtf((float)(c + 1));
    int s = c;
#pragma unroll
    for (int d = 1; d < 64; d <<= 1) {
        int t2 = __shfl_up(s, d);
        if (lane >= d) s += t2;
    }
    if (lane == 63) wt[w] = s;
    __syncthreads();
    int base = 0;
    for (int i = 0; i < w; i++) base += wt[i];
    if (n < N_NODES) off[n] = base + s - c;
    if (t == 255) bsum[blockIdx.x] = wt[0] + wt[1] + wt[2] + wt[3];
}

// parallel top scan: one block of 512 covers NB_SCAN=391 block sums
__global__ __launch_bounds__(512) void scan_top_kernel(const int* __restrict__ bsum,
                                                       int* __restrict__ bbase) {
    __shared__ int wt[8];
    int t = threadIdx.x, lane = t & 63, w = t >> 6;
    int v = (t < NB_SCAN) ? bsum[t] : 0;
    int s = v;
#pragma unroll
    for (int d = 1; d < 64; d <<= 1) {
        int u = __shfl_up(s, d);
        if (lane >= d) s += u;
    }
    if (lane == 63) wt[w] = s;
    __syncthreads();
    int base = 0;
    for (int i = 0; i < w; i++) base += wt[i];
    if (t < NB_SCAN) bbase[t] = base + s - v;
}

__global__ __launch_bounds__(256) void add_base_kernel(int* __restrict__ off,
                                                       const int* __restrict__ bbase,
                                                       int* __restrict__ cursor) {
    int n = blockIdx.x * 256 + threadIdx.x;
    if (n < N_NODES) {
        int o = off[n] + bbase[n >> 8];
        off[n] = o;
        cursor[n] = o;
    }
}

// fill: group g scatters its bucket's packed edges into its contiguous,
// XCD-local csr region. Working set ~1.7 MB < 4 MB L2 -> full-line writebacks.
__global__ __launch_bounds__(256) void fill_kernel(const int* __restrict__ scur,
                                                   const unsigned* __restrict__ bkt,
                                                   int* __restrict__ cursor,
                                                   int* __restrict__ csr) {
    int g = blockIdx.x & 7;
    int chunk = blockIdx.x >> 3;
    int stride = (gridDim.x >> 3) * 256;
    int base = g * GRP_SZ;
    for (int w = 0; w < 8; w++) {
        int sub = g * 8 + w;
        int nE = scur[sub];
        const unsigned* p = bkt + (size_t)sub * SUBCAP;
        for (int i = chunk * 256 + threadIdx.x; i < nE; i += stride) {
            unsigned pk = p[i];
            int d = base + (int)(pk >> 17);
            int s = (int)(pk & 0x1FFFFu);
            int pos = atomicAdd(&cursor[d], 1);
            csr[pos] = s;
        }
    }
}

// ---------------------------------------------------------------------------
// layer 1 GEMM: y1 = (x @ W1) * dinv.  BM=128 nodes/block, 8x4 micro-tile.
// ---------------------------------------------------------------------------
#define BM1 128
__global__ __launch_bounds__(256) void xw1_kernel(const float* __restrict__ x,
                                                  const float* __restrict__ W1,
                                                  const float* __restrict__ dinv,
                                                  float* __restrict__ y1) {
    __shared__ float Ws[IN_F * HID_F];     // 32 KB
    __shared__ float xs[32][BM1 + 4];      // ~16.9 KB

    const float4* w4 = (const float4*)W1;
    float4* ws4 = (float4*)Ws;
    for (int i = threadIdx.x; i < IN_F * HID_F / 4; i += 256) ws4[i] = w4[i];

    int tid = threadIdx.x;
    int tx = tid & 15, ty = tid >> 4;
    int c0 = tx * 4, r0 = ty * 8;
    int nodeBase = blockIdx.x * BM1;

    float acc[8][4];
#pragma unroll
    for (int i = 0; i < 8; i++)
#pragma unroll
        for (int j = 0; j < 4; j++) acc[i][j] = 0.f;

    int sNode = tid >> 3;        // 0..31
    int sK4 = (tid & 7) * 4;     // 0,4,...,28

    for (int kc = 0; kc < IN_F; kc += 32) {
        __syncthreads();
#pragma unroll
        for (int p = 0; p < 4; p++) {
            int nl = p * 32 + sNode;
            int n = nodeBase + nl;
            float4 v = make_float4(0.f, 0.f, 0.f, 0.f);
            if (n < N_NODES) v = *(const float4*)(x + (size_t)n * IN_F + kc + sK4);
            xs[sK4 + 0][nl] = v.x;
            xs[sK4 + 1][nl] = v.y;
            xs[sK4 + 2][nl] = v.z;
            xs[sK4 + 3][nl] = v.w;
        }
        __syncthreads();
#pragma unroll
        for (int k = 0; k < 32; k++) {
            float4 wv = *(const float4*)(Ws + (kc + k) * HID_F + c0);
            float4 xa = *(const float4*)(&xs[k][r0]);
            float4 xb = *(const float4*)(&xs[k][r0 + 4]);
            float xr[8] = {xa.x, xa.y, xa.z, xa.w, xb.x, xb.y, xb.z, xb.w};
            float wr[4] = {wv.x, wv.y, wv.z, wv.w};
#pragma unroll
            for (int i = 0; i < 8; i++)
#pragma unroll
                for (int j = 0; j < 4; j++) acc[i][j] += xr[i] * wr[j];
        }
    }

#pragma unroll
    for (int i = 0; i < 8; i++) {
        int n = nodeBase + r0 + i;
        if (n < N_NODES) {
            float dv = dinv[n];
            *(float4*)(y1 + (size_t)n * HID_F + c0) =
                make_float4(acc[i][0] * dv, acc[i][1] * dv, acc[i][2] * dv, acc[i][3] * dv);
        }
    }
}

// --- gather layer 1: one wave per node, lane = feature --------------------
__global__ __launch_bounds__(256) void gather1_kernel(const int* __restrict__ off,
                                                      const int* __restrict__ endp,
                                                      const int* __restrict__ csr,
                                                      const float* __restrict__ y1,
                                                      float* __restrict__ agg1) {
    int node = (blockIdx.x * 256 + threadIdx.x) >> 6;
    int lane = threadIdx.x & 63;
    if (node >= N_NODES) return;
    int start = off[node], end = endp[node];

    float acc = y1[(size_t)node * HID_F + lane];   // self loop
    for (int j = start; j < end; j += 64) {
        int m = min(64, end - j);
        int nbr = (lane < m) ? csr[j + lane] : 0;
        int i = 0;
        for (; i + 4 <= m; i += 4) {
            int s0 = __shfl(nbr, i), s1 = __shfl(nbr, i + 1);
            int s2 = __shfl(nbr, i + 2), s3 = __shfl(nbr, i + 3);
            float v0 = y1[(size_t)s0 * HID_F + lane];
            float v1 = y1[(size_t)s1 * HID_F + lane];
            float v2 = y1[(size_t)s2 * HID_F + lane];
            float v3 = y1[(size_t)s3 * HID_F + lane];
            acc += (v0 + v1) + (v2 + v3);
        }
        for (; i < m; i++) {
            int s = __shfl(nbr, i);
            acc += y1[(size_t)s * HID_F + lane];
        }
    }
    agg1[(size_t)node * HID_F + lane] = acc;
}

// ---------------------------------------------------------------------------
// layer 2 GEMM: y2 = (relu(agg1*dinv + b1) @ W2) * dinv.
// ---------------------------------------------------------------------------
#define BM2 128
__global__ __launch_bounds__(256) void layer2_kernel(const float* __restrict__ agg1,
                                                     const float* __restrict__ dinv,
                                                     const float* __restrict__ W2,
                                                     const float* __restrict__ b1,
                                                     float* __restrict__ y2) {
    __shared__ float Ws[HID_F * CLS_F];    // 8 KB
    __shared__ float hs[HID_F][BM2 + 4];   // ~33.8 KB

    const float4* w4 = (const float4*)W2;
    float4* ws4 = (float4*)Ws;
    for (int i = threadIdx.x; i < HID_F * CLS_F / 4; i += 256) ws4[i] = w4[i];

    int tid = threadIdx.x;
    int nodeBase = blockIdx.x * BM2;

    int sNode = tid >> 4;        // 0..15
    int sK4 = (tid & 15) * 4;    // 0..60
    float4 bv = *(const float4*)(b1 + sK4);

#pragma unroll
    for (int p = 0; p < 8; p++) {
        int nl = p * 16 + sNode;
        int n = nodeBase + nl;
        float4 v = make_float4(0.f, 0.f, 0.f, 0.f);
        float dv = 0.f;
        if (n < N_NODES) {
            v = *(const float4*)(agg1 + (size_t)n * HID_F + sK4);
            dv = dinv[n];
        }
        hs[sK4 + 0][nl] = fmaxf(v.x * dv + bv.x, 0.f);
        hs[sK4 + 1][nl] = fmaxf(v.y * dv + bv.y, 0.f);
        hs[sK4 + 2][nl] = fmaxf(v.z * dv + bv.z, 0.f);
        hs[sK4 + 3][nl] = fmaxf(v.w * dv + bv.w, 0.f);
    }
    __syncthreads();

    int tx = tid & 7, ty = tid >> 3;
    int c0 = tx * 4, r0 = ty * 4;

    float acc[4][4];
#pragma unroll
    for (int i = 0; i < 4; i++)
#pragma unroll
        for (int j = 0; j < 4; j++) acc[i][j] = 0.f;

#pragma unroll
    for (int k = 0; k < HID_F; k++) {
        float4 wv = *(const float4*)(Ws + k * CLS_F + c0);
        float4 xa = *(const float4*)(&hs[k][r0]);
        float xr[4] = {xa.x, xa.y, xa.z, xa.w};
        float wr[4] = {wv.x, wv.y, wv.z, wv.w};
#pragma unroll
        for (int i = 0; i < 4; i++)
#pragma unroll
            for (int j = 0; j < 4; j++) acc[i][j] += xr[i] * wr[j];
    }

#pragma unroll
    for (int i = 0; i < 4; i++) {
        int n = nodeBase + r0 + i;
        if (n < N_NODES) {
            float dv = dinv[n];
            *(float4*)(y2 + (size_t)n * CLS_F + c0) =
                make_float4(acc[i][0] * dv, acc[i][1] * dv, acc[i][2] * dv, acc[i][3] * dv);
        }
    }
}

// --- gather layer 2: half-wave (32 lanes) per node ------------------------
__global__ __launch_bounds__(256) void gather2_kernel(const int* __restrict__ off,
                                                      const int* __restrict__ endp,
                                                      const int* __restrict__ csr,
                                                      const float* __restrict__ y2,
                                                      float* __restrict__ agg2) {
    int node = (blockIdx.x * 256 + threadIdx.x) >> 5;
    int lane = threadIdx.x & 31;
    if (node >= N_NODES) return;
    int start = off[node], end = endp[node];

    float acc = y2[(size_t)node * CLS_F + lane];   // self loop
    for (int j = start; j < end; j += 32) {
        int m = min(32, end - j);
        int nbr = (lane < m) ? csr[j + lane] : 0;
        int i = 0;
        for (; i + 4 <= m; i += 4) {
            int s0 = __shfl(nbr, i, 32), s1 = __shfl(nbr, i + 1, 32);
            int s2 = __shfl(nbr, i + 2, 32), s3 = __shfl(nbr, i + 3, 32);
            float v0 = y2[(size_t)s0 * CLS_F + lane];
            float v1 = y2[(size_t)s1 * CLS_F + lane];
            float v2 = y2[(size_t)s2 * CLS_F + lane];
            float v3 = y2[(size_t)s3 * CLS_F + lane];
            acc += (v0 + v1) + (v2 + v3);
        }
        for (; i < m; i++) {
            int s = __shfl(nbr, i, 32);
            acc += y2[(size_t)s * CLS_F + lane];
        }
    }
    agg2[(size_t)node * CLS_F + lane] = acc;
}

// --- epilogue: out = agg2*dinv + b2 ---------------------------------------
__global__ __launch_bounds__(256) void finish_kernel(const float* __restrict__ agg2,
                                                     const float* __restrict__ dinv,
                                                     const float* __restrict__ b2,
                                                     float* __restrict__ out) {
    int gid = blockIdx.x * 256 + threadIdx.x;
    if (gid >= N_NODES * CLS_F) return;
    int n = gid >> 5;
    int c = gid & 31;
    out[gid] = agg2[gid] * dinv[n] + b2[c];
}

extern "C" void kernel_launch(void* const* d_in, const int* in_sizes, int n_in,
                              void* d_out, int out_size, void* d_ws, size_t ws_size,
                              hipStream_t stream) {
    const float* x  = (const float*)d_in[0];
    const int*   ei = (const int*)d_in[1];
    // d_in[2] = edge_attr, unused by GCNConv
    const float* W1 = (const float*)d_in[3];
    const float* b1 = (const float*)d_in[4];
    const float* W2 = (const float*)d_in[5];
    const float* b2 = (const float*)d_in[6];
    float* out = (float*)d_out;

    const int* src = ei;
    const int* dst = ei + N_EDGES;

    char* ws = (char*)d_ws;
    size_t npad = ((size_t)N_NODES * 4 + 255) / 256 * 256;
    float* dinv   = (float*)ws;
    int*   cnt    = (int*)(ws + npad);
    int*   off    = (int*)(ws + 2 * npad);
    int*   cursor = (int*)(ws + 3 * npad);
    int*   bsum   = (int*)(ws + 4 * npad);            // NB_SCAN ints
    int*   bbase  = bsum + 512;                       // NB_SCAN ints
    int*   scur   = bbase + 512;                      // 64 ints
    int*   csr    = (int*)(ws + 4 * npad + 8192);
    unsigned* bkt = (unsigned*)(ws + 4 * npad + 8192 + (size_t)N_EDGES * 4);
    float* y1     = (float*)((char*)bkt + (size_t)64 * SUBCAP * 4);
    float* agg1   = y1 + (size_t)N_NODES * HID_F;
    float* y2     = y1;                                // y1 dead after gather1
    float* agg2   = y1 + (size_t)N_NODES * CLS_F;

    dim3 blk(256);
    int nb_nodes = (N_NODES + 255) / 256;
    init_kernel <<<dim3(nb_nodes), blk, 0, stream>>>(cnt, scur);
    bucket_kernel<<<dim3(N_EDGES / 256), blk, 0, stream>>>(src, dst, scur, bkt);
    count_kernel<<<dim3(1024), blk, 0, stream>>>(scur, bkt, cnt);
    scan_block_kernel<<<dim3(NB_SCAN), blk, 0, stream>>>(cnt, off, bsum, dinv);
    scan_top_kernel<<<dim3(1), dim3(512), 0, stream>>>(bsum, bbase);
    add_base_kernel<<<dim3(nb_nodes), blk, 0, stream>>>(off, bbase, cursor);
    fill_kernel <<<dim3(1024), blk, 0, stream>>>(scur, bkt, cursor, csr);
    xw1_kernel  <<<dim3((N_NODES + BM1 - 1) / BM1), blk, 0, stream>>>(x, W1, dinv, y1);
    gather1_kernel<<<dim3((N_NODES * 64 + 255) / 256), blk, 0, stream>>>(off, cursor, csr, y1, agg1);
    layer2_kernel<<<dim3((N_NODES + BM2 - 1) / BM2), blk, 0, stream>>>(agg1, dinv, W2, b1, y2);
    gather2_kernel<<<dim3((N_NODES * 32 + 255) / 256), blk, 0, stream>>>(off, cursor, csr, y2, agg2);
    finish_kernel<<<dim3((N_NODES * CLS_F + 255) / 256), blk, 0, stream>>>(agg2, dinv, b2, out);
}

// Round 7
// 427.998 us; speedup vs baseline: 4.2113x; 4.2113x over previous
//
#include <hip/hip_runtime.h>

#define N_NODES 100000
#define N_EDGES 1600000
#define IN_F 128
#define HID_F 64
#define CLS_F 32
#define NB_SCAN ((N_NODES + 255) / 256)   // 391
#define NGRP 8
#define GRP_SZ (N_NODES / NGRP)           // 12500
#define EPB 2048                           // edges per partition block
#define NBLK ((N_EDGES + EPB - 1) / EPB)   // 782
#define NVAL (NGRP * NBLK)                 // 6256

// ---------------------------------------------------------------------------
// CSR build v4 — deterministic two-pass radix partition (no global cursors):
//   A: per-block 8-bin LDS histogram -> bh[bin][blk]
//   scan_hist: exclusive scan (bin-major) -> global write offsets
//   B: re-read edges, LDS-atomic rank, write packed (dstLocal<<17|src) -> bkt
//   count/fill: read own bucket's contiguous slice, XCD-local atomics
// ---------------------------------------------------------------------------

__global__ __launch_bounds__(256) void init_kernel(int* __restrict__ cnt) {
    int n = blockIdx.x * 256 + threadIdx.x;
    if (n < N_NODES) cnt[n] = 0;
}

__global__ __launch_bounds__(256) void bucketA_kernel(const int* __restrict__ dst,
                                                      int* __restrict__ bh) {
    __shared__ int h[NGRP];
    if (threadIdx.x < NGRP) h[threadIdx.x] = 0;
    __syncthreads();
    int e0 = blockIdx.x * EPB;
    int e1 = min(e0 + EPB, N_EDGES);
    for (int e = e0 + threadIdx.x; e < e1; e += 256) {
        int g = dst[e] / GRP_SZ;
        atomicAdd(&h[g], 1);
    }
    __syncthreads();
    if (threadIdx.x < NGRP) bh[threadIdx.x * NBLK + blockIdx.x] = h[threadIdx.x];
}

// exclusive scan over NVAL=6256 ints, in place, one 1024-thread block
__global__ __launch_bounds__(1024) void scan_hist_kernel(int* __restrict__ bh) {
    __shared__ int wsum[16];
    const int CH = (NVAL + 1023) / 1024;   // 7
    int t = threadIdx.x;
    int base = t * CH;
    int v[CH];
    int local = 0;
#pragma unroll
    for (int i = 0; i < CH; i++) {
        int idx = base + i;
        int x = (idx < NVAL) ? bh[idx] : 0;
        v[i] = local;
        local += x;
    }
    int lane = t & 63, w = t >> 6;
    int s = local;
#pragma unroll
    for (int d = 1; d < 64; d <<= 1) {
        int u = __shfl_up(s, d);
        if (lane >= d) s += u;
    }
    if (lane == 63) wsum[w] = s;
    __syncthreads();
    int wbase = 0;
    for (int i = 0; i < w; i++) wbase += wsum[i];
    int tbase = wbase + s - local;
#pragma unroll
    for (int i = 0; i < CH; i++) {
        int idx = base + i;
        if (idx < NVAL) bh[idx] = tbase + v[i];
    }
}

__global__ __launch_bounds__(256) void bucketB_kernel(const int* __restrict__ src,
                                                      const int* __restrict__ dst,
                                                      const int* __restrict__ bhScan,
                                                      unsigned* __restrict__ bkt) {
    __shared__ int cur[NGRP];
    if (threadIdx.x < NGRP) cur[threadIdx.x] = bhScan[threadIdx.x * NBLK + blockIdx.x];
    __syncthreads();
    int e0 = blockIdx.x * EPB;
    int e1 = min(e0 + EPB, N_EDGES);
    for (int e = e0 + threadIdx.x; e < e1; e += 256) {
        int d = dst[e];
        int g = d / GRP_SZ;
        unsigned pk = ((unsigned)(d - g * GRP_SZ) << 17) | (unsigned)src[e];
        int pos = atomicAdd(&cur[g], 1);   // LDS atomic — no global round-trip
        bkt[pos] = pk;
    }
}

// count: group g = blockIdx&7 histograms its bucket's contiguous slice
__global__ __launch_bounds__(256) void count_kernel(const int* __restrict__ bhScan,
                                                    const unsigned* __restrict__ bkt,
                                                    int* __restrict__ cnt) {
    int g = blockIdx.x & 7;
    int chunk = blockIdx.x >> 3;
    int stride = (gridDim.x >> 3) * 256;
    int s0 = bhScan[g * NBLK];
    int s1 = (g < 7) ? bhScan[(g + 1) * NBLK] : N_EDGES;
    int base = g * GRP_SZ;
    for (int i = s0 + chunk * 256 + threadIdx.x; i < s1; i += stride)
        atomicAdd(&cnt[base + (int)(bkt[i] >> 17)], 1);
}

// per-256-block exclusive scan of cnt -> off (local), block total -> bsum,
// dinv = rsqrt(cnt+1)
__global__ __launch_bounds__(256) void scan_block_kernel(const int* __restrict__ cnt,
                                                         int* __restrict__ off,
                                                         int* __restrict__ bsum,
                                                         float* __restrict__ dinv) {
    __shared__ int wt[4];
    int t = threadIdx.x;
    int n = blockIdx.x * 256 + t;
    int lane = t & 63, w = t >> 6;
    int c = (n < N_NODES) ? cnt[n] : 0;
    if (n < N_NODES) dinv[n] = rsqrtf((float)(c + 1));
    int s = c;
#pragma unroll
    for (int d = 1; d < 64; d <<= 1) {
        int t2 = __shfl_up(s, d);
        if (lane >= d) s += t2;
    }
    if (lane == 63) wt[w] = s;
    __syncthreads();
    int base = 0;
    for (int i = 0; i < w; i++) base += wt[i];
    if (n < N_NODES) off[n] = base + s - c;
    if (t == 255) bsum[blockIdx.x] = wt[0] + wt[1] + wt[2] + wt[3];
}

// parallel top scan: one block of 512 covers NB_SCAN=391 block sums
__global__ __launch_bounds__(512) void scan_top_kernel(const int* __restrict__ bsum,
                                                       int* __restrict__ bbase) {
    __shared__ int wt[8];
    int t = threadIdx.x, lane = t & 63, w = t >> 6;
    int v = (t < NB_SCAN) ? bsum[t] : 0;
    int s = v;
#pragma unroll
    for (int d = 1; d < 64; d <<= 1) {
        int u = __shfl_up(s, d);
        if (lane >= d) s += u;
    }
    if (lane == 63) wt[w] = s;
    __syncthreads();
    int base = 0;
    for (int i = 0; i < w; i++) base += wt[i];
    if (t < NB_SCAN) bbase[t] = base + s - v;
}

__global__ __launch_bounds__(256) void add_base_kernel(int* __restrict__ off,
                                                       const int* __restrict__ bbase,
                                                       int* __restrict__ cursor) {
    int n = blockIdx.x * 256 + threadIdx.x;
    if (n < N_NODES) {
        int o = off[n] + bbase[n >> 8];
        off[n] = o;
        cursor[n] = o;
    }
}

// fill: group g scatters its bucket's slice into its contiguous csr region
__global__ __launch_bounds__(256) void fill_kernel(const int* __restrict__ bhScan,
                                                   const unsigned* __restrict__ bkt,
                                                   int* __restrict__ cursor,
                                                   int* __restrict__ csr) {
    int g = blockIdx.x & 7;
    int chunk = blockIdx.x >> 3;
    int stride = (gridDim.x >> 3) * 256;
    int s0 = bhScan[g * NBLK];
    int s1 = (g < 7) ? bhScan[(g + 1) * NBLK] : N_EDGES;
    int base = g * GRP_SZ;
    for (int i = s0 + chunk * 256 + threadIdx.x; i < s1; i += stride) {
        unsigned pk = bkt[i];
        int d = base + (int)(pk >> 17);
        int pos = atomicAdd(&cursor[d], 1);
        csr[pos] = (int)(pk & 0x1FFFFu);
    }
}

// ---------------------------------------------------------------------------
// layer 1 GEMM: y1 = (x @ W1) * dinv.  BM=128 nodes/block, 8x4 micro-tile.
// ---------------------------------------------------------------------------
#define BM1 128
__global__ __launch_bounds__(256) void xw1_kernel(const float* __restrict__ x,
                                                  const float* __restrict__ W1,
                                                  const float* __restrict__ dinv,
                                                  float* __restrict__ y1) {
    __shared__ float Ws[IN_F * HID_F];     // 32 KB
    __shared__ float xs[32][BM1 + 4];      // ~16.9 KB

    const float4* w4 = (const float4*)W1;
    float4* ws4 = (float4*)Ws;
    for (int i = threadIdx.x; i < IN_F * HID_F / 4; i += 256) ws4[i] = w4[i];

    int tid = threadIdx.x;
    int tx = tid & 15, ty = tid >> 4;
    int c0 = tx * 4, r0 = ty * 8;
    int nodeBase = blockIdx.x * BM1;

    float acc[8][4];
#pragma unroll
    for (int i = 0; i < 8; i++)
#pragma unroll
        for (int j = 0; j < 4; j++) acc[i][j] = 0.f;

    int sNode = tid >> 3;        // 0..31
    int sK4 = (tid & 7) * 4;     // 0,4,...,28

    for (int kc = 0; kc < IN_F; kc += 32) {
        __syncthreads();
#pragma unroll
        for (int p = 0; p < 4; p++) {
            int nl = p * 32 + sNode;
            int n = nodeBase + nl;
            float4 v = make_float4(0.f, 0.f, 0.f, 0.f);
            if (n < N_NODES) v = *(const float4*)(x + (size_t)n * IN_F + kc + sK4);
            xs[sK4 + 0][nl] = v.x;
            xs[sK4 + 1][nl] = v.y;
            xs[sK4 + 2][nl] = v.z;
            xs[sK4 + 3][nl] = v.w;
        }
        __syncthreads();
#pragma unroll
        for (int k = 0; k < 32; k++) {
            float4 wv = *(const float4*)(Ws + (kc + k) * HID_F + c0);
            float4 xa = *(const float4*)(&xs[k][r0]);
            float4 xb = *(const float4*)(&xs[k][r0 + 4]);
            float xr[8] = {xa.x, xa.y, xa.z, xa.w, xb.x, xb.y, xb.z, xb.w};
            float wr[4] = {wv.x, wv.y, wv.z, wv.w};
#pragma unroll
            for (int i = 0; i < 8; i++)
#pragma unroll
                for (int j = 0; j < 4; j++) acc[i][j] += xr[i] * wr[j];
        }
    }

#pragma unroll
    for (int i = 0; i < 8; i++) {
        int n = nodeBase + r0 + i;
        if (n < N_NODES) {
            float dv = dinv[n];
            *(float4*)(y1 + (size_t)n * HID_F + c0) =
                make_float4(acc[i][0] * dv, acc[i][1] * dv, acc[i][2] * dv, acc[i][3] * dv);
        }
    }
}

// --- gather layer 1: one wave per node, lane = feature --------------------
__global__ __launch_bounds__(256) void gather1_kernel(const int* __restrict__ off,
                                                      const int* __restrict__ endp,
                                                      const int* __restrict__ csr,
                                                      const float* __restrict__ y1,
                                                      float* __restrict__ agg1) {
    int node = (blockIdx.x * 256 + threadIdx.x) >> 6;
    int lane = threadIdx.x & 63;
    if (node >= N_NODES) return;
    int start = off[node], end = endp[node];

    float acc = y1[(size_t)node * HID_F + lane];   // self loop
    for (int j = start; j < end; j += 64) {
        int m = min(64, end - j);
        int nbr = (lane < m) ? csr[j + lane] : 0;
        int i = 0;
        for (; i + 4 <= m; i += 4) {
            int s0 = __shfl(nbr, i), s1 = __shfl(nbr, i + 1);
            int s2 = __shfl(nbr, i + 2), s3 = __shfl(nbr, i + 3);
            float v0 = y1[(size_t)s0 * HID_F + lane];
            float v1 = y1[(size_t)s1 * HID_F + lane];
            float v2 = y1[(size_t)s2 * HID_F + lane];
            float v3 = y1[(size_t)s3 * HID_F + lane];
            acc += (v0 + v1) + (v2 + v3);
        }
        for (; i < m; i++) {
            int s = __shfl(nbr, i);
            acc += y1[(size_t)s * HID_F + lane];
        }
    }
    agg1[(size_t)node * HID_F + lane] = acc;
}

// ---------------------------------------------------------------------------
// layer 2 GEMM: y2 = (relu(agg1*dinv + b1) @ W2) * dinv.
// ---------------------------------------------------------------------------
#define BM2 128
__global__ __launch_bounds__(256) void layer2_kernel(const float* __restrict__ agg1,
                                                     const float* __restrict__ dinv,
                                                     const float* __restrict__ W2,
                                                     const float* __restrict__ b1,
                                                     float* __restrict__ y2) {
    __shared__ float Ws[HID_F * CLS_F];    // 8 KB
    __shared__ float hs[HID_F][BM2 + 4];   // ~33.8 KB

    const float4* w4 = (const float4*)W2;
    float4* ws4 = (float4*)Ws;
    for (int i = threadIdx.x; i < HID_F * CLS_F / 4; i += 256) ws4[i] = w4[i];

    int tid = threadIdx.x;
    int nodeBase = blockIdx.x * BM2;

    int sNode = tid >> 4;        // 0..15
    int sK4 = (tid & 15) * 4;    // 0..60
    float4 bv = *(const float4*)(b1 + sK4);

#pragma unroll
    for (int p = 0; p < 8; p++) {
        int nl = p * 16 + sNode;
        int n = nodeBase + nl;
        float4 v = make_float4(0.f, 0.f, 0.f, 0.f);
        float dv = 0.f;
        if (n < N_NODES) {
            v = *(const float4*)(agg1 + (size_t)n * HID_F + sK4);
            dv = dinv[n];
        }
        hs[sK4 + 0][nl] = fmaxf(v.x * dv + bv.x, 0.f);
        hs[sK4 + 1][nl] = fmaxf(v.y * dv + bv.y, 0.f);
        hs[sK4 + 2][nl] = fmaxf(v.z * dv + bv.z, 0.f);
        hs[sK4 + 3][nl] = fmaxf(v.w * dv + bv.w, 0.f);
    }
    __syncthreads();

    int tx = tid & 7, ty = tid >> 3;
    int c0 = tx * 4, r0 = ty * 4;

    float acc[4][4];
#pragma unroll
    for (int i = 0; i < 4; i++)
#pragma unroll
        for (int j = 0; j < 4; j++) acc[i][j] = 0.f;

#pragma unroll
    for (int k = 0; k < HID_F; k++) {
        float4 wv = *(const float4*)(Ws + k * CLS_F + c0);
        float4 xa = *(const float4*)(&hs[k][r0]);
        float xr[4] = {xa.x, xa.y, xa.z, xa.w};
        float wr[4] = {wv.x, wv.y, wv.z, wv.w};
#pragma unroll
        for (int i = 0; i < 4; i++)
#pragma unroll
            for (int j = 0; j < 4; j++) acc[i][j] += xr[i] * wr[j];
    }

#pragma unroll
    for (int i = 0; i < 4; i++) {
        int n = nodeBase + r0 + i;
        if (n < N_NODES) {
            float dv = dinv[n];
            *(float4*)(y2 + (size_t)n * CLS_F + c0) =
                make_float4(acc[i][0] * dv, acc[i][1] * dv, acc[i][2] * dv, acc[i][3] * dv);
        }
    }
}

// --- gather layer 2: half-wave (32 lanes) per node ------------------------
__global__ __launch_bounds__(256) void gather2_kernel(const int* __restrict__ off,
                                                      const int* __restrict__ endp,
                                                      const int* __restrict__ csr,
                                                      const float* __restrict__ y2,
                                                      float* __restrict__ agg2) {
    int node = (blockIdx.x * 256 + threadIdx.x) >> 5;
    int lane = threadIdx.x & 31;
    if (node >= N_NODES) return;
    int start = off[node], end = endp[node];

    float acc = y2[(size_t)node * CLS_F + lane];   // self loop
    for (int j = start; j < end; j += 32) {
        int m = min(32, end - j);
        int nbr = (lane < m) ? csr[j + lane] : 0;
        int i = 0;
        for (; i + 4 <= m; i += 4) {
            int s0 = __shfl(nbr, i, 32), s1 = __shfl(nbr, i + 1, 32);
            int s2 = __shfl(nbr, i + 2, 32), s3 = __shfl(nbr, i + 3, 32);
            float v0 = y2[(size_t)s0 * CLS_F + lane];
            float v1 = y2[(size_t)s1 * CLS_F + lane];
            float v2 = y2[(size_t)s2 * CLS_F + lane];
            float v3 = y2[(size_t)s3 * CLS_F + lane];
            acc += (v0 + v1) + (v2 + v3);
        }
        for (; i < m; i++) {
            int s = __shfl(nbr, i, 32);
            acc += y2[(size_t)s * CLS_F + lane];
        }
    }
    agg2[(size_t)node * CLS_F + lane] = acc;
}

// --- epilogue: out = agg2*dinv + b2 ---------------------------------------
__global__ __launch_bounds__(256) void finish_kernel(const float* __restrict__ agg2,
                                                     const float* __restrict__ dinv,
                                                     const float* __restrict__ b2,
                                                     float* __restrict__ out) {
    int gid = blockIdx.x * 256 + threadIdx.x;
    if (gid >= N_NODES * CLS_F) return;
    int n = gid >> 5;
    int c = gid & 31;
    out[gid] = agg2[gid] * dinv[n] + b2[c];
}

extern "C" void kernel_launch(void* const* d_in, const int* in_sizes, int n_in,
                              void* d_out, int out_size, void* d_ws, size_t ws_size,
                              hipStream_t stream) {
    const float* x  = (const float*)d_in[0];
    const int*   ei = (const int*)d_in[1];
    // d_in[2] = edge_attr, unused by GCNConv
    const float* W1 = (const float*)d_in[3];
    const float* b1 = (const float*)d_in[4];
    const float* W2 = (const float*)d_in[5];
    const float* b2 = (const float*)d_in[6];
    float* out = (float*)d_out;

    const int* src = ei;
    const int* dst = ei + N_EDGES;

    char* ws = (char*)d_ws;
    size_t npad = ((size_t)N_NODES * 4 + 255) / 256 * 256;
    float* dinv   = (float*)ws;
    int*   cnt    = (int*)(ws + npad);
    int*   off    = (int*)(ws + 2 * npad);
    int*   cursor = (int*)(ws + 3 * npad);
    int*   bsum   = (int*)(ws + 4 * npad);            // NB_SCAN ints
    int*   bbase  = bsum + 512;                       // NB_SCAN ints
    int*   bh     = bbase + 512;                      // NVAL=6256 ints
    int*   csr    = (int*)(ws + 4 * npad + 32768);
    unsigned* bkt = (unsigned*)(ws + 4 * npad + 32768 + (size_t)N_EDGES * 4);
    float* y1     = (float*)((char*)bkt + (size_t)N_EDGES * 4);
    float* agg1   = y1 + (size_t)N_NODES * HID_F;
    float* y2     = y1;                                // y1 dead after gather1
    float* agg2   = y1 + (size_t)N_NODES * CLS_F;

    dim3 blk(256);
    int nb_nodes = (N_NODES + 255) / 256;
    init_kernel   <<<dim3(nb_nodes), blk, 0, stream>>>(cnt);
    bucketA_kernel<<<dim3(NBLK), blk, 0, stream>>>(dst, bh);
    scan_hist_kernel<<<dim3(1), dim3(1024), 0, stream>>>(bh);
    bucketB_kernel<<<dim3(NBLK), blk, 0, stream>>>(src, dst, bh, bkt);
    count_kernel  <<<dim3(1024), blk, 0, stream>>>(bh, bkt, cnt);
    scan_block_kernel<<<dim3(NB_SCAN), blk, 0, stream>>>(cnt, off, bsum, dinv);
    scan_top_kernel<<<dim3(1), dim3(512), 0, stream>>>(bsum, bbase);
    add_base_kernel<<<dim3(nb_nodes), blk, 0, stream>>>(off, bbase, cursor);
    fill_kernel   <<<dim3(1024), blk, 0, stream>>>(bh, bkt, cursor, csr);
    xw1_kernel    <<<dim3((N_NODES + BM1 - 1) / BM1), blk, 0, stream>>>(x, W1, dinv, y1);
    gather1_kernel<<<dim3((N_NODES * 64 + 255) / 256), blk, 0, stream>>>(off, cursor, csr, y1, agg1);
    layer2_kernel <<<dim3((N_NODES + BM2 - 1) / BM2), blk, 0, stream>>>(agg1, dinv, W2, b1, y2);
    gather2_kernel<<<dim3((N_NODES * 32 + 255) / 256), blk, 0, stream>>>(off, cursor, csr, y2, agg2);
    finish_kernel <<<dim3((N_NODES * CLS_F + 255) / 256), blk, 0, stream>>>(agg2, dinv, b2, out);
}

// Round 8
// 346.277 us; speedup vs baseline: 5.2051x; 1.2360x over previous
//
#include <hip/hip_runtime.h>

#define N_NODES 100000
#define N_EDGES 1600000
#define IN_F 128
#define HID_F 64
#define CLS_F 32

#define NBKT 200                 // buckets of 500 dst nodes each
#define BKT_NODES 500
#define EPB 16384                // edges per partition block
#define NBLK 98                  // ceil(1600000/16384)
#define NVAL (NBKT * NBLK)       // 19600
#define CAP 8960                 // LDS staging capacity; mean 8000, sigma ~89

// ---------------------------------------------------------------------------
// CSR build v5 — per-bucket LDS counting sort, streaming csr writes:
//   bucketA: per-block 200-bin histogram -> bh[bucket][blk]
//   scan_hist: exclusive scan of 19600 -> deterministic write offsets
//   bucketB: scatter packed (dstLocal<<17|src) into bucket-major bkt
//   sort_bucket: block b owns bucket b: LDS hist -> scan -> LDS scatter ->
//     sequential stream to csr; writes off/endp/dinv non-atomically.
// ---------------------------------------------------------------------------

__global__ __launch_bounds__(256) void bucketA_kernel(const int* __restrict__ dst,
                                                      int* __restrict__ bh) {
    __shared__ int h[NBKT];
    for (int i = threadIdx.x; i < NBKT; i += 256) h[i] = 0;
    __syncthreads();
    int e0 = blockIdx.x * EPB;
    int e1 = min(e0 + EPB, N_EDGES);
    for (int e = e0 + threadIdx.x; e < e1; e += 256)
        atomicAdd(&h[dst[e] / BKT_NODES], 1);
    __syncthreads();
    for (int i = threadIdx.x; i < NBKT; i += 256)
        bh[i * NBLK + blockIdx.x] = h[i];
}

// exclusive scan over NVAL=19600 ints, in place, one 1024-thread block
__global__ __launch_bounds__(1024) void scan_hist_kernel(int* __restrict__ bh) {
    __shared__ int wsum[16];
    const int CH = (NVAL + 1023) / 1024;   // 20
    int t = threadIdx.x;
    int base = t * CH;
    int v[CH];
    int local = 0;
#pragma unroll
    for (int i = 0; i < CH; i++) {
        int idx = base + i;
        int x = (idx < NVAL) ? bh[idx] : 0;
        v[i] = local;
        local += x;
    }
    int lane = t & 63, w = t >> 6;
    int s = local;
#pragma unroll
    for (int d = 1; d < 64; d <<= 1) {
        int u = __shfl_up(s, d);
        if (lane >= d) s += u;
    }
    if (lane == 63) wsum[w] = s;
    __syncthreads();
    int wbase = 0;
    for (int i = 0; i < w; i++) wbase += wsum[i];
    int tbase = wbase + s - local;
#pragma unroll
    for (int i = 0; i < CH; i++) {
        int idx = base + i;
        if (idx < NVAL) bh[idx] = tbase + v[i];
    }
}

__global__ __launch_bounds__(256) void bucketB_kernel(const int* __restrict__ src,
                                                      const int* __restrict__ dst,
                                                      const int* __restrict__ bhScan,
                                                      unsigned* __restrict__ bkt) {
    __shared__ int cur[NBKT];
    for (int i = threadIdx.x; i < NBKT; i += 256)
        cur[i] = bhScan[i * NBLK + blockIdx.x];
    __syncthreads();
    int e0 = blockIdx.x * EPB;
    int e1 = min(e0 + EPB, N_EDGES);
    for (int e = e0 + threadIdx.x; e < e1; e += 256) {
        int d = dst[e];
        int g = d / BKT_NODES;
        unsigned pk = ((unsigned)(d - g * BKT_NODES) << 17) | (unsigned)src[e];
        int pos = atomicAdd(&cur[g], 1);   // LDS atomic, deterministic base
        bkt[pos] = pk;
    }
}

// block b sorts bucket b (≈8000 edges, 500 nodes) entirely in LDS, streams out
__global__ __launch_bounds__(256) void sort_bucket_kernel(const int* __restrict__ bhScan,
                                                          const unsigned* __restrict__ bkt,
                                                          int* __restrict__ csr,
                                                          int* __restrict__ off,
                                                          int* __restrict__ endp,
                                                          float* __restrict__ dinv) {
    __shared__ int hist[BKT_NODES];
    __shared__ int loff[BKT_NODES];
    __shared__ int wt[4];
    __shared__ int csrS[CAP];
    int b = blockIdx.x;
    int t = threadIdx.x;
    int s0 = bhScan[b * NBLK];
    int s1 = (b < NBKT - 1) ? bhScan[(b + 1) * NBLK] : N_EDGES;
    int nE = s1 - s0;

    for (int i = t; i < BKT_NODES; i += 256) hist[i] = 0;
    __syncthreads();
    for (int i = t; i < nE; i += 256)
        atomicAdd(&hist[bkt[s0 + i] >> 17], 1);
    __syncthreads();

    // exclusive scan of hist[500]: thread t owns j=2t, 2t+1 (t<250)
    int h0 = 0, h1 = 0;
    if (t < 250) { h0 = hist[2 * t]; h1 = hist[2 * t + 1]; }
    int sum = h0 + h1;
    int lane = t & 63, w = t >> 6;
    int s = sum;
#pragma unroll
    for (int d = 1; d < 64; d <<= 1) {
        int u = __shfl_up(s, d);
        if (lane >= d) s += u;
    }
    if (lane == 63) wt[w] = s;
    __syncthreads();
    int wbase = 0;
    for (int i = 0; i < w; i++) wbase += wt[i];
    int excl = wbase + s - sum;
    if (t < 250) { loff[2 * t] = excl; loff[2 * t + 1] = excl + h0; }
    __syncthreads();

    // write per-node outputs (block owns node range [b*500, b*500+500))
    for (int j = t; j < BKT_NODES; j += 256) {
        int n = b * BKT_NODES + j;
        int c = hist[j];
        int o = s0 + loff[j];
        off[n] = o;
        endp[n] = o + c;
        dinv[n] = rsqrtf((float)(c + 1));
    }
    __syncthreads();

    // scatter into LDS csr staging (loff reused as cursors)
    for (int i = t; i < nE; i += 256) {
        unsigned pk = bkt[s0 + i];
        int dl = (int)(pk >> 17);
        int p = atomicAdd(&loff[dl], 1);
        int sv = (int)(pk & 0x1FFFFu);
        if (p < CAP) csrS[p] = sv;
        else csr[s0 + p] = sv;   // overflow fallback, still correct position
    }
    __syncthreads();

    // stream out — sequential full-line stores
    int lim = min(nE, CAP);
    for (int i = t; i < lim; i += 256) csr[s0 + i] = csrS[i];
}

// ---------------------------------------------------------------------------
// layer 1 GEMM: y1 = (x @ W1) * dinv.  BM=128 nodes/block, 8x4 micro-tile.
// ---------------------------------------------------------------------------
#define BM1 128
__global__ __launch_bounds__(256) void xw1_kernel(const float* __restrict__ x,
                                                  const float* __restrict__ W1,
                                                  const float* __restrict__ dinv,
                                                  float* __restrict__ y1) {
    __shared__ float Ws[IN_F * HID_F];     // 32 KB
    __shared__ float xs[32][BM1 + 4];      // ~16.9 KB

    const float4* w4 = (const float4*)W1;
    float4* ws4 = (float4*)Ws;
    for (int i = threadIdx.x; i < IN_F * HID_F / 4; i += 256) ws4[i] = w4[i];

    int tid = threadIdx.x;
    int tx = tid & 15, ty = tid >> 4;
    int c0 = tx * 4, r0 = ty * 8;
    int nodeBase = blockIdx.x * BM1;

    float acc[8][4];
#pragma unroll
    for (int i = 0; i < 8; i++)
#pragma unroll
        for (int j = 0; j < 4; j++) acc[i][j] = 0.f;

    int sNode = tid >> 3;        // 0..31
    int sK4 = (tid & 7) * 4;     // 0,4,...,28

    for (int kc = 0; kc < IN_F; kc += 32) {
        __syncthreads();
#pragma unroll
        for (int p = 0; p < 4; p++) {
            int nl = p * 32 + sNode;
            int n = nodeBase + nl;
            float4 v = make_float4(0.f, 0.f, 0.f, 0.f);
            if (n < N_NODES) v = *(const float4*)(x + (size_t)n * IN_F + kc + sK4);
            xs[sK4 + 0][nl] = v.x;
            xs[sK4 + 1][nl] = v.y;
            xs[sK4 + 2][nl] = v.z;
            xs[sK4 + 3][nl] = v.w;
        }
        __syncthreads();
#pragma unroll
        for (int k = 0; k < 32; k++) {
            float4 wv = *(const float4*)(Ws + (kc + k) * HID_F + c0);
            float4 xa = *(const float4*)(&xs[k][r0]);
            float4 xb = *(const float4*)(&xs[k][r0 + 4]);
            float xr[8] = {xa.x, xa.y, xa.z, xa.w, xb.x, xb.y, xb.z, xb.w};
            float wr[4] = {wv.x, wv.y, wv.z, wv.w};
#pragma unroll
            for (int i = 0; i < 8; i++)
#pragma unroll
                for (int j = 0; j < 4; j++) acc[i][j] += xr[i] * wr[j];
        }
    }

#pragma unroll
    for (int i = 0; i < 8; i++) {
        int n = nodeBase + r0 + i;
        if (n < N_NODES) {
            float dv = dinv[n];
            *(float4*)(y1 + (size_t)n * HID_F + c0) =
                make_float4(acc[i][0] * dv, acc[i][1] * dv, acc[i][2] * dv, acc[i][3] * dv);
        }
    }
}

// --- gather layer 1: one wave per node, lane = feature --------------------
__global__ __launch_bounds__(256) void gather1_kernel(const int* __restrict__ off,
                                                      const int* __restrict__ endp,
                                                      const int* __restrict__ csr,
                                                      const float* __restrict__ y1,
                                                      float* __restrict__ agg1) {
    int node = (blockIdx.x * 256 + threadIdx.x) >> 6;
    int lane = threadIdx.x & 63;
    if (node >= N_NODES) return;
    int start = off[node], end = endp[node];

    float acc = y1[(size_t)node * HID_F + lane];   // self loop
    for (int j = start; j < end; j += 64) {
        int m = min(64, end - j);
        int nbr = (lane < m) ? csr[j + lane] : 0;
        int i = 0;
        for (; i + 4 <= m; i += 4) {
            int s0 = __shfl(nbr, i), s1 = __shfl(nbr, i + 1);
            int s2 = __shfl(nbr, i + 2), s3 = __shfl(nbr, i + 3);
            float v0 = y1[(size_t)s0 * HID_F + lane];
            float v1 = y1[(size_t)s1 * HID_F + lane];
            float v2 = y1[(size_t)s2 * HID_F + lane];
            float v3 = y1[(size_t)s3 * HID_F + lane];
            acc += (v0 + v1) + (v2 + v3);
        }
        for (; i < m; i++) {
            int s = __shfl(nbr, i);
            acc += y1[(size_t)s * HID_F + lane];
        }
    }
    agg1[(size_t)node * HID_F + lane] = acc;
}

// ---------------------------------------------------------------------------
// layer 2 GEMM: y2 = (relu(agg1*dinv + b1) @ W2) * dinv.
// ---------------------------------------------------------------------------
#define BM2 128
__global__ __launch_bounds__(256) void layer2_kernel(const float* __restrict__ agg1,
                                                     const float* __restrict__ dinv,
                                                     const float* __restrict__ W2,
                                                     const float* __restrict__ b1,
                                                     float* __restrict__ y2) {
    __shared__ float Ws[HID_F * CLS_F];    // 8 KB
    __shared__ float hs[HID_F][BM2 + 4];   // ~33.8 KB

    const float4* w4 = (const float4*)W2;
    float4* ws4 = (float4*)Ws;
    for (int i = threadIdx.x; i < HID_F * CLS_F / 4; i += 256) ws4[i] = w4[i];

    int tid = threadIdx.x;
    int nodeBase = blockIdx.x * BM2;

    int sNode = tid >> 4;        // 0..15
    int sK4 = (tid & 15) * 4;    // 0..60
    float4 bv = *(const float4*)(b1 + sK4);

#pragma unroll
    for (int p = 0; p < 8; p++) {
        int nl = p * 16 + sNode;
        int n = nodeBase + nl;
        float4 v = make_float4(0.f, 0.f, 0.f, 0.f);
        float dv = 0.f;
        if (n < N_NODES) {
            v = *(const float4*)(agg1 + (size_t)n * HID_F + sK4);
            dv = dinv[n];
        }
        hs[sK4 + 0][nl] = fmaxf(v.x * dv + bv.x, 0.f);
        hs[sK4 + 1][nl] = fmaxf(v.y * dv + bv.y, 0.f);
        hs[sK4 + 2][nl] = fmaxf(v.z * dv + bv.z, 0.f);
        hs[sK4 + 3][nl] = fmaxf(v.w * dv + bv.w, 0.f);
    }
    __syncthreads();

    int tx = tid & 7, ty = tid >> 3;
    int c0 = tx * 4, r0 = ty * 4;

    float acc[4][4];
#pragma unroll
    for (int i = 0; i < 4; i++)
#pragma unroll
        for (int j = 0; j < 4; j++) acc[i][j] = 0.f;

#pragma unroll
    for (int k = 0; k < HID_F; k++) {
        float4 wv = *(const float4*)(Ws + k * CLS_F + c0);
        float4 xa = *(const float4*)(&hs[k][r0]);
        float xr[4] = {xa.x, xa.y, xa.z, xa.w};
        float wr[4] = {wv.x, wv.y, wv.z, wv.w};
#pragma unroll
        for (int i = 0; i < 4; i++)
#pragma unroll
            for (int j = 0; j < 4; j++) acc[i][j] += xr[i] * wr[j];
    }

#pragma unroll
    for (int i = 0; i < 4; i++) {
        int n = nodeBase + r0 + i;
        if (n < N_NODES) {
            float dv = dinv[n];
            *(float4*)(y2 + (size_t)n * CLS_F + c0) =
                make_float4(acc[i][0] * dv, acc[i][1] * dv, acc[i][2] * dv, acc[i][3] * dv);
        }
    }
}

// --- gather layer 2: half-wave (32 lanes) per node ------------------------
__global__ __launch_bounds__(256) void gather2_kernel(const int* __restrict__ off,
                                                      const int* __restrict__ endp,
                                                      const int* __restrict__ csr,
                                                      const float* __restrict__ y2,
                                                      float* __restrict__ agg2) {
    int node = (blockIdx.x * 256 + threadIdx.x) >> 5;
    int lane = threadIdx.x & 31;
    if (node >= N_NODES) return;
    int start = off[node], end = endp[node];

    float acc = y2[(size_t)node * CLS_F + lane];   // self loop
    for (int j = start; j < end; j += 32) {
        int m = min(32, end - j);
        int nbr = (lane < m) ? csr[j + lane] : 0;
        int i = 0;
        for (; i + 4 <= m; i += 4) {
            int s0 = __shfl(nbr, i, 32), s1 = __shfl(nbr, i + 1, 32);
            int s2 = __shfl(nbr, i + 2, 32), s3 = __shfl(nbr, i + 3, 32);
            float v0 = y2[(size_t)s0 * CLS_F + lane];
            float v1 = y2[(size_t)s1 * CLS_F + lane];
            float v2 = y2[(size_t)s2 * CLS_F + lane];
            float v3 = y2[(size_t)s3 * CLS_F + lane];
            acc += (v0 + v1) + (v2 + v3);
        }
        for (; i < m; i++) {
            int s = __shfl(nbr, i, 32);
            acc += y2[(size_t)s * CLS_F + lane];
        }
    }
    agg2[(size_t)node * CLS_F + lane] = acc;
}

// --- epilogue: out = agg2*dinv + b2 ---------------------------------------
__global__ __launch_bounds__(256) void finish_kernel(const float* __restrict__ agg2,
                                                     const float* __restrict__ dinv,
                                                     const float* __restrict__ b2,
                                                     float* __restrict__ out) {
    int gid = blockIdx.x * 256 + threadIdx.x;
    if (gid >= N_NODES * CLS_F) return;
    int n = gid >> 5;
    int c = gid & 31;
    out[gid] = agg2[gid] * dinv[n] + b2[c];
}

extern "C" void kernel_launch(void* const* d_in, const int* in_sizes, int n_in,
                              void* d_out, int out_size, void* d_ws, size_t ws_size,
                              hipStream_t stream) {
    const float* x  = (const float*)d_in[0];
    const int*   ei = (const int*)d_in[1];
    // d_in[2] = edge_attr, unused by GCNConv
    const float* W1 = (const float*)d_in[3];
    const float* b1 = (const float*)d_in[4];
    const float* W2 = (const float*)d_in[5];
    const float* b2 = (const float*)d_in[6];
    float* out = (float*)d_out;

    const int* src = ei;
    const int* dst = ei + N_EDGES;

    char* ws = (char*)d_ws;
    size_t npad = ((size_t)N_NODES * 4 + 255) / 256 * 256;
    float* dinv = (float*)ws;
    int*   off  = (int*)(ws + npad);
    int*   endp = (int*)(ws + 2 * npad);
    int*   bh   = (int*)(ws + 3 * npad);              // NVAL=19600 ints
    int*   csr  = (int*)(ws + 3 * npad + 81920);
    unsigned* bkt = (unsigned*)((char*)csr + (size_t)N_EDGES * 4);
    float* y1   = (float*)((char*)bkt + (size_t)N_EDGES * 4);
    float* agg1 = y1 + (size_t)N_NODES * HID_F;
    float* y2   = y1;                                  // y1 dead after gather1
    float* agg2 = y1 + (size_t)N_NODES * CLS_F;

    dim3 blk(256);
    bucketA_kernel  <<<dim3(NBLK), blk, 0, stream>>>(dst, bh);
    scan_hist_kernel<<<dim3(1), dim3(1024), 0, stream>>>(bh);
    bucketB_kernel  <<<dim3(NBLK), blk, 0, stream>>>(src, dst, bh, bkt);
    sort_bucket_kernel<<<dim3(NBKT), blk, 0, stream>>>(bh, bkt, csr, off, endp, dinv);
    xw1_kernel      <<<dim3((N_NODES + BM1 - 1) / BM1), blk, 0, stream>>>(x, W1, dinv, y1);
    gather1_kernel  <<<dim3((N_NODES * 64 + 255) / 256), blk, 0, stream>>>(off, endp, csr, y1, agg1);
    layer2_kernel   <<<dim3((N_NODES + BM2 - 1) / BM2), blk, 0, stream>>>(agg1, dinv, W2, b1, y2);
    gather2_kernel  <<<dim3((N_NODES * 32 + 255) / 256), blk, 0, stream>>>(off, endp, csr, y2, agg2);
    finish_kernel   <<<dim3((N_NODES * CLS_F + 255) / 256), blk, 0, stream>>>(agg2, dinv, b2, out);
}

// Round 9
// 311.915 us; speedup vs baseline: 5.7786x; 1.1102x over previous
//
#include <hip/hip_runtime.h>

#define N_NODES 100000
#define N_EDGES 1600000
#define IN_F 128
#define HID_F 64
#define CLS_F 32

#define NBKT 200                 // buckets of 500 dst nodes each
#define BKT_NODES 500
#define EPB 16384                // edges per partition block
#define NBLK 98                  // ceil(1600000/16384)
#define NVAL (NBKT * NBLK)       // 19600
#define CAP 8960                 // LDS staging capacity; mean 8000, sigma ~89

__device__ __forceinline__ float b2f(unsigned short u) {
    union { unsigned i; float f; } c; c.i = ((unsigned)u) << 16; return c.f;
}
__device__ __forceinline__ unsigned short f2b(float f) {
    union { float f; unsigned i; } c; c.f = f;
    unsigned r = c.i + 0x7FFFu + ((c.i >> 16) & 1u);   // round-nearest-even
    return (unsigned short)(r >> 16);
}

// ---------------------------------------------------------------------------
// CSR build v5 — per-bucket LDS counting sort (unchanged from round 8)
// ---------------------------------------------------------------------------

__global__ __launch_bounds__(256) void bucketA_kernel(const int* __restrict__ dst,
                                                      int* __restrict__ bh) {
    __shared__ int h[NBKT];
    for (int i = threadIdx.x; i < NBKT; i += 256) h[i] = 0;
    __syncthreads();
    int e0 = blockIdx.x * EPB;
    int e1 = min(e0 + EPB, N_EDGES);
    for (int e = e0 + threadIdx.x; e < e1; e += 256)
        atomicAdd(&h[dst[e] / BKT_NODES], 1);
    __syncthreads();
    for (int i = threadIdx.x; i < NBKT; i += 256)
        bh[i * NBLK + blockIdx.x] = h[i];
}

__global__ __launch_bounds__(1024) void scan_hist_kernel(int* __restrict__ bh) {
    __shared__ int wsum[16];
    const int CH = (NVAL + 1023) / 1024;   // 20
    int t = threadIdx.x;
    int base = t * CH;
    int v[CH];
    int local = 0;
#pragma unroll
    for (int i = 0; i < CH; i++) {
        int idx = base + i;
        int x = (idx < NVAL) ? bh[idx] : 0;
        v[i] = local;
        local += x;
    }
    int lane = t & 63, w = t >> 6;
    int s = local;
#pragma unroll
    for (int d = 1; d < 64; d <<= 1) {
        int u = __shfl_up(s, d);
        if (lane >= d) s += u;
    }
    if (lane == 63) wsum[w] = s;
    __syncthreads();
    int wbase = 0;
    for (int i = 0; i < w; i++) wbase += wsum[i];
    int tbase = wbase + s - local;
#pragma unroll
    for (int i = 0; i < CH; i++) {
        int idx = base + i;
        if (idx < NVAL) bh[idx] = tbase + v[i];
    }
}

__global__ __launch_bounds__(256) void bucketB_kernel(const int* __restrict__ src,
                                                      const int* __restrict__ dst,
                                                      const int* __restrict__ bhScan,
                                                      unsigned* __restrict__ bkt) {
    __shared__ int cur[NBKT];
    for (int i = threadIdx.x; i < NBKT; i += 256)
        cur[i] = bhScan[i * NBLK + blockIdx.x];
    __syncthreads();
    int e0 = blockIdx.x * EPB;
    int e1 = min(e0 + EPB, N_EDGES);
    for (int e = e0 + threadIdx.x; e < e1; e += 256) {
        int d = dst[e];
        int g = d / BKT_NODES;
        unsigned pk = ((unsigned)(d - g * BKT_NODES) << 17) | (unsigned)src[e];
        int pos = atomicAdd(&cur[g], 1);
        bkt[pos] = pk;
    }
}

__global__ __launch_bounds__(256) void sort_bucket_kernel(const int* __restrict__ bhScan,
                                                          const unsigned* __restrict__ bkt,
                                                          int* __restrict__ csr,
                                                          int* __restrict__ off,
                                                          int* __restrict__ endp,
                                                          float* __restrict__ dinv) {
    __shared__ int hist[BKT_NODES];
    __shared__ int loff[BKT_NODES];
    __shared__ int wt[4];
    __shared__ int csrS[CAP];
    int b = blockIdx.x;
    int t = threadIdx.x;
    int s0 = bhScan[b * NBLK];
    int s1 = (b < NBKT - 1) ? bhScan[(b + 1) * NBLK] : N_EDGES;
    int nE = s1 - s0;

    for (int i = t; i < BKT_NODES; i += 256) hist[i] = 0;
    __syncthreads();
    for (int i = t; i < nE; i += 256)
        atomicAdd(&hist[bkt[s0 + i] >> 17], 1);
    __syncthreads();

    int h0 = 0, h1 = 0;
    if (t < 250) { h0 = hist[2 * t]; h1 = hist[2 * t + 1]; }
    int sum = h0 + h1;
    int lane = t & 63, w = t >> 6;
    int s = sum;
#pragma unroll
    for (int d = 1; d < 64; d <<= 1) {
        int u = __shfl_up(s, d);
        if (lane >= d) s += u;
    }
    if (lane == 63) wt[w] = s;
    __syncthreads();
    int wbase = 0;
    for (int i = 0; i < w; i++) wbase += wt[i];
    int excl = wbase + s - sum;
    if (t < 250) { loff[2 * t] = excl; loff[2 * t + 1] = excl + h0; }
    __syncthreads();

    for (int j = t; j < BKT_NODES; j += 256) {
        int n = b * BKT_NODES + j;
        int c = hist[j];
        int o = s0 + loff[j];
        off[n] = o;
        endp[n] = o + c;
        dinv[n] = rsqrtf((float)(c + 1));
    }
    __syncthreads();

    for (int i = t; i < nE; i += 256) {
        unsigned pk = bkt[s0 + i];
        int dl = (int)(pk >> 17);
        int p = atomicAdd(&loff[dl], 1);
        int sv = (int)(pk & 0x1FFFFu);
        if (p < CAP) csrS[p] = sv;
        else csr[s0 + p] = sv;
    }
    __syncthreads();

    int lim = min(nE, CAP);
    for (int i = t; i < lim; i += 256) csr[s0 + i] = csrS[i];
}

// ---------------------------------------------------------------------------
// layer 1 GEMM: y1h = bf16((x @ W1) * dinv).  BM=128, BK=16, 8x4 micro-tile.
// LDS = 32K (Ws) + 8K (xs) = 40 KB exactly -> 4 blocks/CU.
// ---------------------------------------------------------------------------
#define BM1 128
#define BK1 16
__global__ __launch_bounds__(256) void xw1_kernel(const float* __restrict__ x,
                                                  const float* __restrict__ W1,
                                                  const float* __restrict__ dinv,
                                                  unsigned short* __restrict__ y1h) {
    __shared__ float Ws[IN_F * HID_F];     // 32 KB
    __shared__ float xs[BK1][BM1];         // 8 KB, stride 128

    const float4* w4 = (const float4*)W1;
    float4* ws4 = (float4*)Ws;
    for (int i = threadIdx.x; i < IN_F * HID_F / 4; i += 256) ws4[i] = w4[i];

    int tid = threadIdx.x;
    int tx = tid & 15, ty = tid >> 4;
    int c0 = tx * 4, r0 = ty * 8;
    int nodeBase = blockIdx.x * BM1;

    float acc[8][4];
#pragma unroll
    for (int i = 0; i < 8; i++)
#pragma unroll
        for (int j = 0; j < 4; j++) acc[i][j] = 0.f;

    int sNode = tid >> 2;        // 0..63
    int sK4 = (tid & 3) * 4;     // 0,4,8,12

    for (int kc = 0; kc < IN_F; kc += BK1) {
        __syncthreads();
#pragma unroll
        for (int p = 0; p < 2; p++) {
            int nl = p * 64 + sNode;
            int n = nodeBase + nl;
            float4 v = make_float4(0.f, 0.f, 0.f, 0.f);
            if (n < N_NODES) v = *(const float4*)(x + (size_t)n * IN_F + kc + sK4);
            xs[sK4 + 0][nl] = v.x;
            xs[sK4 + 1][nl] = v.y;
            xs[sK4 + 2][nl] = v.z;
            xs[sK4 + 3][nl] = v.w;
        }
        __syncthreads();
#pragma unroll
        for (int k = 0; k < BK1; k++) {
            float4 wv = *(const float4*)(Ws + (kc + k) * HID_F + c0);
            float4 xa = *(const float4*)(&xs[k][r0]);
            float4 xb = *(const float4*)(&xs[k][r0 + 4]);
            float xr[8] = {xa.x, xa.y, xa.z, xa.w, xb.x, xb.y, xb.z, xb.w};
            float wr[4] = {wv.x, wv.y, wv.z, wv.w};
#pragma unroll
            for (int i = 0; i < 8; i++)
#pragma unroll
                for (int j = 0; j < 4; j++) acc[i][j] += xr[i] * wr[j];
        }
    }

#pragma unroll
    for (int i = 0; i < 8; i++) {
        int n = nodeBase + r0 + i;
        if (n < N_NODES) {
            float dv = dinv[n];
            ushort4 o;
            o.x = f2b(acc[i][0] * dv);
            o.y = f2b(acc[i][1] * dv);
            o.z = f2b(acc[i][2] * dv);
            o.w = f2b(acc[i][3] * dv);
            *(ushort4*)(y1h + (size_t)n * HID_F + c0) = o;
        }
    }
}

// --- gather layer 1: one wave per node, lane = feature, bf16 rows ---------
__global__ __launch_bounds__(256) void gather1_kernel(const int* __restrict__ off,
                                                      const int* __restrict__ endp,
                                                      const int* __restrict__ csr,
                                                      const unsigned short* __restrict__ y1h,
                                                      float* __restrict__ agg1) {
    int node = (blockIdx.x * 256 + threadIdx.x) >> 6;
    int lane = threadIdx.x & 63;
    if (node >= N_NODES) return;
    int start = off[node], end = endp[node];

    float acc = b2f(y1h[(size_t)node * HID_F + lane]);   // self loop
    for (int j = start; j < end; j += 64) {
        int m = min(64, end - j);
        int nbr = (lane < m) ? csr[j + lane] : 0;
        int i = 0;
        for (; i + 4 <= m; i += 4) {
            int s0 = __shfl(nbr, i), s1 = __shfl(nbr, i + 1);
            int s2 = __shfl(nbr, i + 2), s3 = __shfl(nbr, i + 3);
            float v0 = b2f(y1h[(size_t)s0 * HID_F + lane]);
            float v1 = b2f(y1h[(size_t)s1 * HID_F + lane]);
            float v2 = b2f(y1h[(size_t)s2 * HID_F + lane]);
            float v3 = b2f(y1h[(size_t)s3 * HID_F + lane]);
            acc += (v0 + v1) + (v2 + v3);
        }
        for (; i < m; i++) {
            int s = __shfl(nbr, i);
            acc += b2f(y1h[(size_t)s * HID_F + lane]);
        }
    }
    agg1[(size_t)node * HID_F + lane] = acc;
}

// ---------------------------------------------------------------------------
// layer 2 GEMM: y2h = bf16((relu(agg1*dinv + b1) @ W2) * dinv).
// ---------------------------------------------------------------------------
#define BM2 128
__global__ __launch_bounds__(256) void layer2_kernel(const float* __restrict__ agg1,
                                                     const float* __restrict__ dinv,
                                                     const float* __restrict__ W2,
                                                     const float* __restrict__ b1,
                                                     unsigned short* __restrict__ y2h) {
    __shared__ float Ws[HID_F * CLS_F];    // 8 KB
    __shared__ float hs[HID_F][BM2 + 4];   // ~33.8 KB

    const float4* w4 = (const float4*)W2;
    float4* ws4 = (float4*)Ws;
    for (int i = threadIdx.x; i < HID_F * CLS_F / 4; i += 256) ws4[i] = w4[i];

    int tid = threadIdx.x;
    int nodeBase = blockIdx.x * BM2;

    int sNode = tid >> 4;        // 0..15
    int sK4 = (tid & 15) * 4;    // 0..60
    float4 bv = *(const float4*)(b1 + sK4);

#pragma unroll
    for (int p = 0; p < 8; p++) {
        int nl = p * 16 + sNode;
        int n = nodeBase + nl;
        float4 v = make_float4(0.f, 0.f, 0.f, 0.f);
        float dv = 0.f;
        if (n < N_NODES) {
            v = *(const float4*)(agg1 + (size_t)n * HID_F + sK4);
            dv = dinv[n];
        }
        hs[sK4 + 0][nl] = fmaxf(v.x * dv + bv.x, 0.f);
        hs[sK4 + 1][nl] = fmaxf(v.y * dv + bv.y, 0.f);
        hs[sK4 + 2][nl] = fmaxf(v.z * dv + bv.z, 0.f);
        hs[sK4 + 3][nl] = fmaxf(v.w * dv + bv.w, 0.f);
    }
    __syncthreads();

    int tx = tid & 7, ty = tid >> 3;
    int c0 = tx * 4, r0 = ty * 4;

    float acc[4][4];
#pragma unroll
    for (int i = 0; i < 4; i++)
#pragma unroll
        for (int j = 0; j < 4; j++) acc[i][j] = 0.f;

#pragma unroll
    for (int k = 0; k < HID_F; k++) {
        float4 wv = *(const float4*)(Ws + k * CLS_F + c0);
        float4 xa = *(const float4*)(&hs[k][r0]);
        float xr[4] = {xa.x, xa.y, xa.z, xa.w};
        float wr[4] = {wv.x, wv.y, wv.z, wv.w};
#pragma unroll
        for (int i = 0; i < 4; i++)
#pragma unroll
            for (int j = 0; j < 4; j++) acc[i][j] += xr[i] * wr[j];
    }

#pragma unroll
    for (int i = 0; i < 4; i++) {
        int n = nodeBase + r0 + i;
        if (n < N_NODES) {
            float dv = dinv[n];
            ushort4 o;
            o.x = f2b(acc[i][0] * dv);
            o.y = f2b(acc[i][1] * dv);
            o.z = f2b(acc[i][2] * dv);
            o.w = f2b(acc[i][3] * dv);
            *(ushort4*)(y2h + (size_t)n * CLS_F + c0) = o;
        }
    }
}

// --- gather layer 2 + fused epilogue: out = acc*dinv + b2 -----------------
__global__ __launch_bounds__(256) void gather2_kernel(const int* __restrict__ off,
                                                      const int* __restrict__ endp,
                                                      const int* __restrict__ csr,
                                                      const unsigned short* __restrict__ y2h,
                                                      const float* __restrict__ dinv,
                                                      const float* __restrict__ b2,
                                                      float* __restrict__ out) {
    int node = (blockIdx.x * 256 + threadIdx.x) >> 5;
    int lane = threadIdx.x & 31;
    if (node >= N_NODES) return;
    int start = off[node], end = endp[node];

    float acc = b2f(y2h[(size_t)node * CLS_F + lane]);   // self loop
    for (int j = start; j < end; j += 32) {
        int m = min(32, end - j);
        int nbr = (lane < m) ? csr[j + lane] : 0;
        int i = 0;
        for (; i + 4 <= m; i += 4) {
            int s0 = __shfl(nbr, i, 32), s1 = __shfl(nbr, i + 1, 32);
            int s2 = __shfl(nbr, i + 2, 32), s3 = __shfl(nbr, i + 3, 32);
            float v0 = b2f(y2h[(size_t)s0 * CLS_F + lane]);
            float v1 = b2f(y2h[(size_t)s1 * CLS_F + lane]);
            float v2 = b2f(y2h[(size_t)s2 * CLS_F + lane]);
            float v3 = b2f(y2h[(size_t)s3 * CLS_F + lane]);
            acc += (v0 + v1) + (v2 + v3);
        }
        for (; i < m; i++) {
            int s = __shfl(nbr, i, 32);
            acc += b2f(y2h[(size_t)s * CLS_F + lane]);
        }
    }
    out[(size_t)node * CLS_F + lane] = acc * dinv[node] + b2[lane];
}

extern "C" void kernel_launch(void* const* d_in, const int* in_sizes, int n_in,
                              void* d_out, int out_size, void* d_ws, size_t ws_size,
                              hipStream_t stream) {
    const float* x  = (const float*)d_in[0];
    const int*   ei = (const int*)d_in[1];
    // d_in[2] = edge_attr, unused by GCNConv
    const float* W1 = (const float*)d_in[3];
    const float* b1 = (const float*)d_in[4];
    const float* W2 = (const float*)d_in[5];
    const float* b2 = (const float*)d_in[6];
    float* out = (float*)d_out;

    const int* src = ei;
    const int* dst = ei + N_EDGES;

    char* ws = (char*)d_ws;
    size_t npad = ((size_t)N_NODES * 4 + 255) / 256 * 256;
    float* dinv = (float*)ws;
    int*   off  = (int*)(ws + npad);
    int*   endp = (int*)(ws + 2 * npad);
    int*   bh   = (int*)(ws + 3 * npad);              // NVAL=19600 ints
    int*   csr  = (int*)(ws + 3 * npad + 81920);
    unsigned* bkt = (unsigned*)((char*)csr + (size_t)N_EDGES * 4);
    unsigned short* y1h = (unsigned short*)((char*)bkt + (size_t)N_EDGES * 4);  // N*64 bf16
    unsigned short* y2h = y1h;                         // y1h dead after gather1 (N*32 bf16)
    float* agg1 = (float*)((char*)y1h + (size_t)N_NODES * HID_F * 2);

    dim3 blk(256);
    bucketA_kernel  <<<dim3(NBLK), blk, 0, stream>>>(dst, bh);
    scan_hist_kernel<<<dim3(1), dim3(1024), 0, stream>>>(bh);
    bucketB_kernel  <<<dim3(NBLK), blk, 0, stream>>>(src, dst, bh, bkt);
    sort_bucket_kernel<<<dim3(NBKT), blk, 0, stream>>>(bh, bkt, csr, off, endp, dinv);
    xw1_kernel      <<<dim3((N_NODES + BM1 - 1) / BM1), blk, 0, stream>>>(x, W1, dinv, y1h);
    gather1_kernel  <<<dim3((N_NODES * 64 + 255) / 256), blk, 0, stream>>>(off, endp, csr, y1h, agg1);
    layer2_kernel   <<<dim3((N_NODES + BM2 - 1) / BM2), blk, 0, stream>>>(agg1, dinv, W2, b1, y2h);
    gather2_kernel  <<<dim3((N_NODES * 32 + 255) / 256), blk, 0, stream>>>(off, endp, csr, y2h, dinv, b2, out);
}

// Round 10
// 303.228 us; speedup vs baseline: 5.9441x; 1.0286x over previous
//
#include <hip/hip_runtime.h>

#define N_NODES 100000
#define N_EDGES 1600000
#define IN_F 128
#define HID_F 64
#define CLS_F 32

#define NBKT 512                 // buckets of 196 dst nodes each
#define BKT_NODES 196
#define EPB 16384                // edges per partition block
#define NBLK 98                  // ceil(1600000/16384)
#define NVAL (NBKT * NBLK)       // 50176
#define CAP 3584                 // LDS staging capacity; mean 3136, sigma ~56

typedef short s8v __attribute__((ext_vector_type(8)));
typedef float f4v __attribute__((ext_vector_type(4)));

__device__ __forceinline__ float b2f(unsigned short u) {
    union { unsigned i; float f; } c; c.i = ((unsigned)u) << 16; return c.f;
}
__device__ __forceinline__ unsigned short f2b(float f) {
    union { float f; unsigned i; } c; c.f = f;
    unsigned r = c.i + 0x7FFFu + ((c.i >> 16) & 1u);   // round-nearest-even
    return (unsigned short)(r >> 16);
}

// ---------------------------------------------------------------------------
// CSR build v5 — per-bucket LDS counting sort (512 buckets for occupancy)
// ---------------------------------------------------------------------------

__global__ __launch_bounds__(256) void bucketA_kernel(const int* __restrict__ dst,
                                                      int* __restrict__ bh) {
    __shared__ int h[NBKT];
    for (int i = threadIdx.x; i < NBKT; i += 256) h[i] = 0;
    __syncthreads();
    int e0 = blockIdx.x * EPB;
    int e1 = min(e0 + EPB, N_EDGES);
    for (int e = e0 + threadIdx.x; e < e1; e += 256)
        atomicAdd(&h[dst[e] / BKT_NODES], 1);
    __syncthreads();
    for (int i = threadIdx.x; i < NBKT; i += 256)
        bh[i * NBLK + blockIdx.x] = h[i];
}

__global__ __launch_bounds__(1024) void scan_hist_kernel(int* __restrict__ bh) {
    __shared__ int wsum[16];
    const int CH = (NVAL + 1023) / 1024;   // 49
    int t = threadIdx.x;
    int base = t * CH;
    int v[CH];
    int local = 0;
#pragma unroll
    for (int i = 0; i < CH; i++) {
        int idx = base + i;
        int x = (idx < NVAL) ? bh[idx] : 0;
        v[i] = local;
        local += x;
    }
    int lane = t & 63, w = t >> 6;
    int s = local;
#pragma unroll
    for (int d = 1; d < 64; d <<= 1) {
        int u = __shfl_up(s, d);
        if (lane >= d) s += u;
    }
    if (lane == 63) wsum[w] = s;
    __syncthreads();
    int wbase = 0;
    for (int i = 0; i < w; i++) wbase += wsum[i];
    int tbase = wbase + s - local;
#pragma unroll
    for (int i = 0; i < CH; i++) {
        int idx = base + i;
        if (idx < NVAL) bh[idx] = tbase + v[i];
    }
}

__global__ __launch_bounds__(256) void bucketB_kernel(const int* __restrict__ src,
                                                      const int* __restrict__ dst,
                                                      const int* __restrict__ bhScan,
                                                      unsigned* __restrict__ bkt) {
    __shared__ int cur[NBKT];
    for (int i = threadIdx.x; i < NBKT; i += 256)
        cur[i] = bhScan[i * NBLK + blockIdx.x];
    __syncthreads();
    int e0 = blockIdx.x * EPB;
    int e1 = min(e0 + EPB, N_EDGES);
    for (int e = e0 + threadIdx.x; e < e1; e += 256) {
        int d = dst[e];
        int g = d / BKT_NODES;
        unsigned pk = ((unsigned)(d - g * BKT_NODES) << 17) | (unsigned)src[e];
        int pos = atomicAdd(&cur[g], 1);
        bkt[pos] = pk;
    }
}

__global__ __launch_bounds__(256) void sort_bucket_kernel(const int* __restrict__ bhScan,
                                                          const unsigned* __restrict__ bkt,
                                                          int* __restrict__ csr,
                                                          int* __restrict__ off,
                                                          int* __restrict__ endp,
                                                          float* __restrict__ dinv) {
    __shared__ int hist[BKT_NODES];
    __shared__ int loff[BKT_NODES];
    __shared__ int wt[4];
    __shared__ int csrS[CAP];
    int b = blockIdx.x;
    int t = threadIdx.x;
    int s0 = bhScan[b * NBLK];
    int s1 = (b < NBKT - 1) ? bhScan[(b + 1) * NBLK] : N_EDGES;
    int nE = s1 - s0;

    for (int i = t; i < BKT_NODES; i += 256) hist[i] = 0;
    __syncthreads();
    for (int i = t; i < nE; i += 256)
        atomicAdd(&hist[bkt[s0 + i] >> 17], 1);
    __syncthreads();

    int h0 = 0, h1 = 0;
    if (t < 98) { h0 = hist[2 * t]; h1 = hist[2 * t + 1]; }
    int sum = h0 + h1;
    int lane = t & 63, w = t >> 6;
    int s = sum;
#pragma unroll
    for (int d = 1; d < 64; d <<= 1) {
        int u = __shfl_up(s, d);
        if (lane >= d) s += u;
    }
    if (lane == 63) wt[w] = s;
    __syncthreads();
    int wbase = 0;
    for (int i = 0; i < w; i++) wbase += wt[i];
    int excl = wbase + s - sum;
    if (t < 98) { loff[2 * t] = excl; loff[2 * t + 1] = excl + h0; }
    __syncthreads();

    for (int j = t; j < BKT_NODES; j += 256) {
        int n = b * BKT_NODES + j;
        if (n < N_NODES) {
            int c = hist[j];
            int o = s0 + loff[j];
            off[n] = o;
            endp[n] = o + c;
            dinv[n] = rsqrtf((float)(c + 1));
        }
    }
    __syncthreads();

    for (int i = t; i < nE; i += 256) {
        unsigned pk = bkt[s0 + i];
        int dl = (int)(pk >> 17);
        int p = atomicAdd(&loff[dl], 1);
        int sv = (int)(pk & 0x1FFFFu);
        if (p < CAP) csrS[p] = sv;
        else csr[s0 + p] = sv;
    }
    __syncthreads();

    int lim = min(nE, CAP);
    for (int i = t; i < lim; i += 256) csr[s0 + i] = csrS[i];
}

// ---------------------------------------------------------------------------
// layer 1 GEMM via MFMA bf16: y1h = bf16((x @ W1) * dinv).
// Block = 64 nodes, 4 waves; wave w owns node rows [16w,16w+16).
// K = 128 in 4 chunks of 32; N = 64 in 4 tiles of 16.
// A-frag (m89): lane L holds A[m = L&15][k = (L>>4)*8 + j], j=0..7
// B-frag:       lane L holds B[k = (L>>4)*8 + j][n = L&15]
// C/D (m89):    lane L holds D[row = (L>>4)*4 + r][col = L&15]
// ---------------------------------------------------------------------------
#define XBM 64
__global__ __launch_bounds__(256) void xw1_kernel(const float* __restrict__ x,
                                                  const float* __restrict__ W1,
                                                  const float* __restrict__ dinv,
                                                  unsigned short* __restrict__ y1h) {
    __shared__ __align__(16) unsigned short Wb[16 * 64 * 8];   // 16 KB, B-frag packed
    __shared__ __align__(16) unsigned short xb[XBM][IN_F + 8]; // 17 KB, pad 8 -> 2-way banks

    int tid = threadIdx.x;

    // pack W1 (f32 row-major [k][n]) into B-fragment layout, bf16
    for (int i = tid; i < IN_F * HID_F; i += 256) {
        int k = i >> 6, n = i & 63;
        int kc = k >> 5, kw = k & 31;
        int nt = n >> 4, nl = n & 15;
        int quad = kw >> 3, j = kw & 7;
        Wb[(((kc * 4 + nt) * 64) + quad * 16 + nl) * 8 + j] = f2b(W1[i]);
    }

    // stage x tile as bf16: thread t -> node (t>>2), k-range (t&3)*32..+32
    int nodeBase = blockIdx.x * XBM;
    {
        int snl = tid >> 2;
        int sk0 = (tid & 3) * 32;
        int n = nodeBase + snl;
#pragma unroll
        for (int kk = 0; kk < 32; kk += 4) {
            float4 v = make_float4(0.f, 0.f, 0.f, 0.f);
            if (n < N_NODES) v = *(const float4*)(x + (size_t)n * IN_F + sk0 + kk);
            ushort4 o;
            o.x = f2b(v.x); o.y = f2b(v.y); o.z = f2b(v.z); o.w = f2b(v.w);
            *(ushort4*)(&xb[snl][sk0 + kk]) = o;
        }
    }
    __syncthreads();

    int wave = tid >> 6, lane = tid & 63;
    int quad = lane >> 4, l15 = lane & 15;
    int rowBase = wave * 16;

    f4v acc[4];
#pragma unroll
    for (int i = 0; i < 4; i++) acc[i] = (f4v){0.f, 0.f, 0.f, 0.f};

#pragma unroll
    for (int kc = 0; kc < 4; kc++) {
        s8v a = *(const s8v*)(&xb[rowBase + l15][kc * 32 + quad * 8]);
#pragma unroll
        for (int nt = 0; nt < 4; nt++) {
            s8v b = *(const s8v*)(&Wb[((kc * 4 + nt) * 64 + lane) * 8]);
            acc[nt] = __builtin_amdgcn_mfma_f32_16x16x32_bf16(a, b, acc[nt], 0, 0, 0);
        }
    }

    // epilogue: rows rowBase + quad*4 + r, col nt*16 + l15
    float dv[4];
    int n0 = nodeBase + rowBase + quad * 4;
#pragma unroll
    for (int r = 0; r < 4; r++)
        dv[r] = (n0 + r < N_NODES) ? dinv[n0 + r] : 0.f;
#pragma unroll
    for (int nt = 0; nt < 4; nt++) {
#pragma unroll
        for (int r = 0; r < 4; r++) {
            int n = n0 + r;
            if (n < N_NODES)
                y1h[(size_t)n * HID_F + nt * 16 + l15] = f2b(acc[nt][r] * dv[r]);
        }
    }
}

// --- gather layer 1: one wave per node, lane = feature, bf16 rows ---------
__global__ __launch_bounds__(256) void gather1_kernel(const int* __restrict__ off,
                                                      const int* __restrict__ endp,
                                                      const int* __restrict__ csr,
                                                      const unsigned short* __restrict__ y1h,
                                                      float* __restrict__ agg1) {
    int node = (blockIdx.x * 256 + threadIdx.x) >> 6;
    int lane = threadIdx.x & 63;
    if (node >= N_NODES) return;
    int start = off[node], end = endp[node];

    float acc = b2f(y1h[(size_t)node * HID_F + lane]);   // self loop
    for (int j = start; j < end; j += 64) {
        int m = min(64, end - j);
        int nbr = (lane < m) ? csr[j + lane] : 0;
        int i = 0;
        for (; i + 8 <= m; i += 8) {
            int s0 = __shfl(nbr, i),     s1 = __shfl(nbr, i + 1);
            int s2 = __shfl(nbr, i + 2), s3 = __shfl(nbr, i + 3);
            int s4 = __shfl(nbr, i + 4), s5 = __shfl(nbr, i + 5);
            int s6 = __shfl(nbr, i + 6), s7 = __shfl(nbr, i + 7);
            float v0 = b2f(y1h[(size_t)s0 * HID_F + lane]);
            float v1 = b2f(y1h[(size_t)s1 * HID_F + lane]);
            float v2 = b2f(y1h[(size_t)s2 * HID_F + lane]);
            float v3 = b2f(y1h[(size_t)s3 * HID_F + lane]);
            float v4 = b2f(y1h[(size_t)s4 * HID_F + lane]);
            float v5 = b2f(y1h[(size_t)s5 * HID_F + lane]);
            float v6 = b2f(y1h[(size_t)s6 * HID_F + lane]);
            float v7 = b2f(y1h[(size_t)s7 * HID_F + lane]);
            acc += ((v0 + v1) + (v2 + v3)) + ((v4 + v5) + (v6 + v7));
        }
        for (; i < m; i++) {
            int s = __shfl(nbr, i);
            acc += b2f(y1h[(size_t)s * HID_F + lane]);
        }
    }
    agg1[(size_t)node * HID_F + lane] = acc;
}

// ---------------------------------------------------------------------------
// layer 2 GEMM: y2h = bf16((relu(agg1*dinv + b1) @ W2) * dinv).
// ---------------------------------------------------------------------------
#define BM2 128
__global__ __launch_bounds__(256) void layer2_kernel(const float* __restrict__ agg1,
                                                     const float* __restrict__ dinv,
                                                     const float* __restrict__ W2,
                                                     const float* __restrict__ b1,
                                                     unsigned short* __restrict__ y2h) {
    __shared__ float Ws[HID_F * CLS_F];    // 8 KB
    __shared__ float hs[HID_F][BM2 + 4];   // ~33.8 KB

    const float4* w4 = (const float4*)W2;
    float4* ws4 = (float4*)Ws;
    for (int i = threadIdx.x; i < HID_F * CLS_F / 4; i += 256) ws4[i] = w4[i];

    int tid = threadIdx.x;
    int nodeBase = blockIdx.x * BM2;

    int sNode = tid >> 4;        // 0..15
    int sK4 = (tid & 15) * 4;    // 0..60
    float4 bv = *(const float4*)(b1 + sK4);

#pragma unroll
    for (int p = 0; p < 8; p++) {
        int nl = p * 16 + sNode;
        int n = nodeBase + nl;
        float4 v = make_float4(0.f, 0.f, 0.f, 0.f);
        float dv = 0.f;
        if (n < N_NODES) {
            v = *(const float4*)(agg1 + (size_t)n * HID_F + sK4);
            dv = dinv[n];
        }
        hs[sK4 + 0][nl] = fmaxf(v.x * dv + bv.x, 0.f);
        hs[sK4 + 1][nl] = fmaxf(v.y * dv + bv.y, 0.f);
        hs[sK4 + 2][nl] = fmaxf(v.z * dv + bv.z, 0.f);
        hs[sK4 + 3][nl] = fmaxf(v.w * dv + bv.w, 0.f);
    }
    __syncthreads();

    int tx = tid & 7, ty = tid >> 3;
    int c0 = tx * 4, r0 = ty * 4;

    float acc[4][4];
#pragma unroll
    for (int i = 0; i < 4; i++)
#pragma unroll
        for (int j = 0; j < 4; j++) acc[i][j] = 0.f;

#pragma unroll
    for (int k = 0; k < HID_F; k++) {
        float4 wv = *(const float4*)(Ws + k * CLS_F + c0);
        float4 xa = *(const float4*)(&hs[k][r0]);
        float xr[4] = {xa.x, xa.y, xa.z, xa.w};
        float wr[4] = {wv.x, wv.y, wv.z, wv.w};
#pragma unroll
        for (int i = 0; i < 4; i++)
#pragma unroll
            for (int j = 0; j < 4; j++) acc[i][j] += xr[i] * wr[j];
    }

#pragma unroll
    for (int i = 0; i < 4; i++) {
        int n = nodeBase + r0 + i;
        if (n < N_NODES) {
            float dv = dinv[n];
            ushort4 o;
            o.x = f2b(acc[i][0] * dv);
            o.y = f2b(acc[i][1] * dv);
            o.z = f2b(acc[i][2] * dv);
            o.w = f2b(acc[i][3] * dv);
            *(ushort4*)(y2h + (size_t)n * CLS_F + c0) = o;
        }
    }
}

// --- gather layer 2 + fused epilogue: out = acc*dinv + b2 -----------------
__global__ __launch_bounds__(256) void gather2_kernel(const int* __restrict__ off,
                                                      const int* __restrict__ endp,
                                                      const int* __restrict__ csr,
                                                      const unsigned short* __restrict__ y2h,
                                                      const float* __restrict__ dinv,
                                                      const float* __restrict__ b2,
                                                      float* __restrict__ out) {
    int node = (blockIdx.x * 256 + threadIdx.x) >> 5;
    int lane = threadIdx.x & 31;
    if (node >= N_NODES) return;
    int start = off[node], end = endp[node];

    float acc = b2f(y2h[(size_t)node * CLS_F + lane]);   // self loop
    for (int j = start; j < end; j += 32) {
        int m = min(32, end - j);
        int nbr = (lane < m) ? csr[j + lane] : 0;
        int i = 0;
        for (; i + 8 <= m; i += 8) {
            int s0 = __shfl(nbr, i, 32),     s1 = __shfl(nbr, i + 1, 32);
            int s2 = __shfl(nbr, i + 2, 32), s3 = __shfl(nbr, i + 3, 32);
            int s4 = __shfl(nbr, i + 4, 32), s5 = __shfl(nbr, i + 5, 32);
            int s6 = __shfl(nbr, i + 6, 32), s7 = __shfl(nbr, i + 7, 32);
            float v0 = b2f(y2h[(size_t)s0 * CLS_F + lane]);
            float v1 = b2f(y2h[(size_t)s1 * CLS_F + lane]);
            float v2 = b2f(y2h[(size_t)s2 * CLS_F + lane]);
            float v3 = b2f(y2h[(size_t)s3 * CLS_F + lane]);
            float v4 = b2f(y2h[(size_t)s4 * CLS_F + lane]);
            float v5 = b2f(y2h[(size_t)s5 * CLS_F + lane]);
            float v6 = b2f(y2h[(size_t)s6 * CLS_F + lane]);
            float v7 = b2f(y2h[(size_t)s7 * CLS_F + lane]);
            acc += ((v0 + v1) + (v2 + v3)) + ((v4 + v5) + (v6 + v7));
        }
        for (; i < m; i++) {
            int s = __shfl(nbr, i, 32);
            acc += b2f(y2h[(size_t)s * CLS_F + lane]);
        }
    }
    out[(size_t)node * CLS_F + lane] = acc * dinv[node] + b2[lane];
}

extern "C" void kernel_launch(void* const* d_in, const int* in_sizes, int n_in,
                              void* d_out, int out_size, void* d_ws, size_t ws_size,
                              hipStream_t stream) {
    const float* x  = (const float*)d_in[0];
    const int*   ei = (const int*)d_in[1];
    // d_in[2] = edge_attr, unused by GCNConv
    const float* W1 = (const float*)d_in[3];
    const float* b1 = (const float*)d_in[4];
    const float* W2 = (const float*)d_in[5];
    const float* b2 = (const float*)d_in[6];
    float* out = (float*)d_out;

    const int* src = ei;
    const int* dst = ei + N_EDGES;

    char* ws = (char*)d_ws;
    size_t npad = ((size_t)N_NODES * 4 + 255) / 256 * 256;
    float* dinv = (float*)ws;
    int*   off  = (int*)(ws + npad);
    int*   endp = (int*)(ws + 2 * npad);
    int*   bh   = (int*)(ws + 3 * npad);              // NVAL=50176 ints (~200 KB)
    int*   csr  = (int*)(ws + 3 * npad + 204800);
    unsigned* bkt = (unsigned*)((char*)csr + (size_t)N_EDGES * 4);
    unsigned short* y1h = (unsigned short*)((char*)bkt + (size_t)N_EDGES * 4);  // N*64 bf16
    unsigned short* y2h = y1h;                         // y1h dead after gather1
    float* agg1 = (float*)((char*)y1h + (size_t)N_NODES * HID_F * 2);

    dim3 blk(256);
    bucketA_kernel  <<<dim3(NBLK), blk, 0, stream>>>(dst, bh);
    scan_hist_kernel<<<dim3(1), dim3(1024), 0, stream>>>(bh);
    bucketB_kernel  <<<dim3(NBLK), blk, 0, stream>>>(src, dst, bh, bkt);
    sort_bucket_kernel<<<dim3(NBKT), blk, 0, stream>>>(bh, bkt, csr, off, endp, dinv);
    xw1_kernel      <<<dim3((N_NODES + XBM - 1) / XBM), blk, 0, stream>>>(x, W1, dinv, y1h);
    gather1_kernel  <<<dim3((N_NODES * 64 + 255) / 256), blk, 0, stream>>>(off, endp, csr, y1h, agg1);
    layer2_kernel   <<<dim3((N_NODES + BM2 - 1) / BM2), blk, 0, stream>>>(agg1, dinv, W2, b1, y2h);
    gather2_kernel  <<<dim3((N_NODES * 32 + 255) / 256), blk, 0, stream>>>(off, endp, csr, y2h, dinv, b2, out);
}

// Round 11
// 269.728 us; speedup vs baseline: 6.6824x; 1.1242x over previous
//
#include <hip/hip_runtime.h>

#define N_NODES 100000
#define N_EDGES 1600000
#define IN_F 128
#define HID_F 64
#define CLS_F 32

#define NBKT 512                 // buckets of 196 dst nodes each
#define BKT_NODES 196
#define EPB 16384                // edges per partition block
#define NBLK 98                  // ceil(1600000/16384)
#define NVAL (NBKT * NBLK)       // 50176
#define CAP 3584                 // LDS staging capacity; mean 3136, sigma ~56

typedef short s8v __attribute__((ext_vector_type(8)));
typedef float f4v __attribute__((ext_vector_type(4)));

__device__ __forceinline__ float b2f(unsigned short u) {
    union { unsigned i; float f; } c; c.i = ((unsigned)u) << 16; return c.f;
}
__device__ __forceinline__ float lo_bf(unsigned u) {
    union { unsigned i; float f; } c; c.i = u << 16; return c.f;
}
__device__ __forceinline__ float hi_bf(unsigned u) {
    union { unsigned i; float f; } c; c.i = u & 0xffff0000u; return c.f;
}
__device__ __forceinline__ unsigned short f2b(float f) {
    union { float f; unsigned i; } c; c.f = f;
    unsigned r = c.i + 0x7FFFu + ((c.i >> 16) & 1u);   // round-nearest-even
    return (unsigned short)(r >> 16);
}

// ---------------------------------------------------------------------------
// CSR build v5 — per-bucket LDS counting sort (unchanged from round 10)
// ---------------------------------------------------------------------------

__global__ __launch_bounds__(256) void bucketA_kernel(const int* __restrict__ dst,
                                                      int* __restrict__ bh) {
    __shared__ int h[NBKT];
    for (int i = threadIdx.x; i < NBKT; i += 256) h[i] = 0;
    __syncthreads();
    int e0 = blockIdx.x * EPB;
    int e1 = min(e0 + EPB, N_EDGES);
    for (int e = e0 + threadIdx.x; e < e1; e += 256)
        atomicAdd(&h[dst[e] / BKT_NODES], 1);
    __syncthreads();
    for (int i = threadIdx.x; i < NBKT; i += 256)
        bh[i * NBLK + blockIdx.x] = h[i];
}

__global__ __launch_bounds__(1024) void scan_hist_kernel(int* __restrict__ bh) {
    __shared__ int wsum[16];
    const int CH = (NVAL + 1023) / 1024;   // 49
    int t = threadIdx.x;
    int base = t * CH;
    int v[CH];
    int local = 0;
#pragma unroll
    for (int i = 0; i < CH; i++) {
        int idx = base + i;
        int x = (idx < NVAL) ? bh[idx] : 0;
        v[i] = local;
        local += x;
    }
    int lane = t & 63, w = t >> 6;
    int s = local;
#pragma unroll
    for (int d = 1; d < 64; d <<= 1) {
        int u = __shfl_up(s, d);
        if (lane >= d) s += u;
    }
    if (lane == 63) wsum[w] = s;
    __syncthreads();
    int wbase = 0;
    for (int i = 0; i < w; i++) wbase += wsum[i];
    int tbase = wbase + s - local;
#pragma unroll
    for (int i = 0; i < CH; i++) {
        int idx = base + i;
        if (idx < NVAL) bh[idx] = tbase + v[i];
    }
}

__global__ __launch_bounds__(256) void bucketB_kernel(const int* __restrict__ src,
                                                      const int* __restrict__ dst,
                                                      const int* __restrict__ bhScan,
                                                      unsigned* __restrict__ bkt) {
    __shared__ int cur[NBKT];
    for (int i = threadIdx.x; i < NBKT; i += 256)
        cur[i] = bhScan[i * NBLK + blockIdx.x];
    __syncthreads();
    int e0 = blockIdx.x * EPB;
    int e1 = min(e0 + EPB, N_EDGES);
    for (int e = e0 + threadIdx.x; e < e1; e += 256) {
        int d = dst[e];
        int g = d / BKT_NODES;
        unsigned pk = ((unsigned)(d - g * BKT_NODES) << 17) | (unsigned)src[e];
        int pos = atomicAdd(&cur[g], 1);
        bkt[pos] = pk;
    }
}

__global__ __launch_bounds__(256) void sort_bucket_kernel(const int* __restrict__ bhScan,
                                                          const unsigned* __restrict__ bkt,
                                                          int* __restrict__ csr,
                                                          int* __restrict__ off,
                                                          int* __restrict__ endp,
                                                          float* __restrict__ dinv) {
    __shared__ int hist[BKT_NODES];
    __shared__ int loff[BKT_NODES];
    __shared__ int wt[4];
    __shared__ int csrS[CAP];
    int b = blockIdx.x;
    int t = threadIdx.x;
    int s0 = bhScan[b * NBLK];
    int s1 = (b < NBKT - 1) ? bhScan[(b + 1) * NBLK] : N_EDGES;
    int nE = s1 - s0;

    for (int i = t; i < BKT_NODES; i += 256) hist[i] = 0;
    __syncthreads();
    for (int i = t; i < nE; i += 256)
        atomicAdd(&hist[bkt[s0 + i] >> 17], 1);
    __syncthreads();

    int h0 = 0, h1 = 0;
    if (t < 98) { h0 = hist[2 * t]; h1 = hist[2 * t + 1]; }
    int sum = h0 + h1;
    int lane = t & 63, w = t >> 6;
    int s = sum;
#pragma unroll
    for (int d = 1; d < 64; d <<= 1) {
        int u = __shfl_up(s, d);
        if (lane >= d) s += u;
    }
    if (lane == 63) wt[w] = s;
    __syncthreads();
    int wbase = 0;
    for (int i = 0; i < w; i++) wbase += wt[i];
    int excl = wbase + s - sum;
    if (t < 98) { loff[2 * t] = excl; loff[2 * t + 1] = excl + h0; }
    __syncthreads();

    for (int j = t; j < BKT_NODES; j += 256) {
        int n = b * BKT_NODES + j;
        if (n < N_NODES) {
            int c = hist[j];
            int o = s0 + loff[j];
            off[n] = o;
            endp[n] = o + c;
            dinv[n] = rsqrtf((float)(c + 1));
        }
    }
    __syncthreads();

    for (int i = t; i < nE; i += 256) {
        unsigned pk = bkt[s0 + i];
        int dl = (int)(pk >> 17);
        int p = atomicAdd(&loff[dl], 1);
        int sv = (int)(pk & 0x1FFFFu);
        if (p < CAP) csrS[p] = sv;
        else csr[s0 + p] = sv;
    }
    __syncthreads();

    int lim = min(nE, CAP);
    for (int i = t; i < lim; i += 256) csr[s0 + i] = csrS[i];
}

// ---------------------------------------------------------------------------
// layer 1 GEMM via MFMA bf16 (unchanged from round 10, verified)
// ---------------------------------------------------------------------------
#define XBM 64
__global__ __launch_bounds__(256) void xw1_kernel(const float* __restrict__ x,
                                                  const float* __restrict__ W1,
                                                  const float* __restrict__ dinv,
                                                  unsigned short* __restrict__ y1h) {
    __shared__ __align__(16) unsigned short Wb[16 * 64 * 8];   // 16 KB, B-frag packed
    __shared__ __align__(16) unsigned short xb[XBM][IN_F + 8]; // 17 KB

    int tid = threadIdx.x;

    for (int i = tid; i < IN_F * HID_F; i += 256) {
        int k = i >> 6, n = i & 63;
        int kc = k >> 5, kw = k & 31;
        int nt = n >> 4, nl = n & 15;
        int quad = kw >> 3, j = kw & 7;
        Wb[(((kc * 4 + nt) * 64) + quad * 16 + nl) * 8 + j] = f2b(W1[i]);
    }

    int nodeBase = blockIdx.x * XBM;
    {
        int snl = tid >> 2;
        int sk0 = (tid & 3) * 32;
        int n = nodeBase + snl;
#pragma unroll
        for (int kk = 0; kk < 32; kk += 4) {
            float4 v = make_float4(0.f, 0.f, 0.f, 0.f);
            if (n < N_NODES) v = *(const float4*)(x + (size_t)n * IN_F + sk0 + kk);
            ushort4 o;
            o.x = f2b(v.x); o.y = f2b(v.y); o.z = f2b(v.z); o.w = f2b(v.w);
            *(ushort4*)(&xb[snl][sk0 + kk]) = o;
        }
    }
    __syncthreads();

    int wave = tid >> 6, lane = tid & 63;
    int quad = lane >> 4, l15 = lane & 15;
    int rowBase = wave * 16;

    f4v acc[4];
#pragma unroll
    for (int i = 0; i < 4; i++) acc[i] = (f4v){0.f, 0.f, 0.f, 0.f};

#pragma unroll
    for (int kc = 0; kc < 4; kc++) {
        s8v a = *(const s8v*)(&xb[rowBase + l15][kc * 32 + quad * 8]);
#pragma unroll
        for (int nt = 0; nt < 4; nt++) {
            s8v b = *(const s8v*)(&Wb[((kc * 4 + nt) * 64 + lane) * 8]);
            acc[nt] = __builtin_amdgcn_mfma_f32_16x16x32_bf16(a, b, acc[nt], 0, 0, 0);
        }
    }

    float dv[4];
    int n0 = nodeBase + rowBase + quad * 4;
#pragma unroll
    for (int r = 0; r < 4; r++)
        dv[r] = (n0 + r < N_NODES) ? dinv[n0 + r] : 0.f;
#pragma unroll
    for (int nt = 0; nt < 4; nt++) {
#pragma unroll
        for (int r = 0; r < 4; r++) {
            int n = n0 + r;
            if (n < N_NODES)
                y1h[(size_t)n * HID_F + nt * 16 + l15] = f2b(acc[nt][r] * dv[r]);
        }
    }
}

// ---------------------------------------------------------------------------
// gather1 + layer2 fused: 32 lanes per node (2 bf16 feats/lane, dword loads),
// 2 nodes per wave. After the gather loop, lane holds agg[2c],agg[2c+1];
// h = relu(agg*dinv+b1); y2[c] = sum_k h[k]*W2[k][c] via 32-step shfl
// reduction with W2 column c in VGPRs (loaded after the loop).
// ---------------------------------------------------------------------------
__global__ __launch_bounds__(256) void gather1_fused_kernel(
        const int* __restrict__ off, const int* __restrict__ endp,
        const int* __restrict__ csr, const unsigned short* __restrict__ y1h,
        const float* __restrict__ dinv, const float* __restrict__ W2,
        const float* __restrict__ b1, unsigned short* __restrict__ y2h) {
    int gid = blockIdx.x * 256 + threadIdx.x;
    int node = gid >> 5;                 // 100000*32 == 12500*256 exactly
    int cl = threadIdx.x & 31;           // lane within node group == output col
    int k2 = 2 * cl;                     // this lane's two feature indices

    int start = off[node], end = endp[node];

    // self loop
    unsigned su = *(const unsigned*)(y1h + (size_t)node * HID_F + k2);
    float a0 = lo_bf(su), a1 = hi_bf(su);

    for (int j = start; j < end; j += 32) {
        int m = min(32, end - j);
        int nbr = (cl < m) ? csr[j + cl] : 0;
        int i = 0;
        for (; i + 4 <= m; i += 4) {
            int s0 = __shfl(nbr, i, 32), s1 = __shfl(nbr, i + 1, 32);
            int s2 = __shfl(nbr, i + 2, 32), s3 = __shfl(nbr, i + 3, 32);
            unsigned u0 = *(const unsigned*)(y1h + (size_t)s0 * HID_F + k2);
            unsigned u1 = *(const unsigned*)(y1h + (size_t)s1 * HID_F + k2);
            unsigned u2 = *(const unsigned*)(y1h + (size_t)s2 * HID_F + k2);
            unsigned u3 = *(const unsigned*)(y1h + (size_t)s3 * HID_F + k2);
            a0 += (lo_bf(u0) + lo_bf(u1)) + (lo_bf(u2) + lo_bf(u3));
            a1 += (hi_bf(u0) + hi_bf(u1)) + (hi_bf(u2) + hi_bf(u3));
        }
        for (; i < m; i++) {
            int s = __shfl(nbr, i, 32);
            unsigned u = *(const unsigned*)(y1h + (size_t)s * HID_F + k2);
            a0 += lo_bf(u);
            a1 += hi_bf(u);
        }
    }

    float dv = dinv[node];
    float2 bb = *(const float2*)(b1 + k2);
    float h0 = fmaxf(a0 * dv + bb.x, 0.f);
    float h1 = fmaxf(a1 * dv + bb.y, 0.f);

    // W2 column cl into registers (after loop: keeps loop VGPR pressure low)
    float w2c[HID_F];
#pragma unroll
    for (int k = 0; k < HID_F; k++) w2c[k] = W2[k * CLS_F + cl];

    float sum = 0.f;
#pragma unroll
    for (int t = 0; t < 32; t++) {
        float hh0 = __shfl(h0, t, 32);
        float hh1 = __shfl(h1, t, 32);
        sum += hh0 * w2c[2 * t] + hh1 * w2c[2 * t + 1];
    }
    y2h[(size_t)node * CLS_F + cl] = f2b(sum * dv);
}

// --- gather layer 2 + fused epilogue: out = acc*dinv + b2 -----------------
__global__ __launch_bounds__(256) void gather2_kernel(const int* __restrict__ off,
                                                      const int* __restrict__ endp,
                                                      const int* __restrict__ csr,
                                                      const unsigned short* __restrict__ y2h,
                                                      const float* __restrict__ dinv,
                                                      const float* __restrict__ b2,
                                                      float* __restrict__ out) {
    int node = (blockIdx.x * 256 + threadIdx.x) >> 5;
    int lane = threadIdx.x & 31;
    if (node >= N_NODES) return;
    int start = off[node], end = endp[node];

    float acc = b2f(y2h[(size_t)node * CLS_F + lane]);   // self loop
    for (int j = start; j < end; j += 32) {
        int m = min(32, end - j);
        int nbr = (lane < m) ? csr[j + lane] : 0;
        int i = 0;
        for (; i + 4 <= m; i += 4) {
            int s0 = __shfl(nbr, i, 32), s1 = __shfl(nbr, i + 1, 32);
            int s2 = __shfl(nbr, i + 2, 32), s3 = __shfl(nbr, i + 3, 32);
            float v0 = b2f(y2h[(size_t)s0 * CLS_F + lane]);
            float v1 = b2f(y2h[(size_t)s1 * CLS_F + lane]);
            float v2 = b2f(y2h[(size_t)s2 * CLS_F + lane]);
            float v3 = b2f(y2h[(size_t)s3 * CLS_F + lane]);
            acc += (v0 + v1) + (v2 + v3);
        }
        for (; i < m; i++) {
            int s = __shfl(nbr, i, 32);
            acc += b2f(y2h[(size_t)s * CLS_F + lane]);
        }
    }
    out[(size_t)node * CLS_F + lane] = acc * dinv[node] + b2[lane];
}

extern "C" void kernel_launch(void* const* d_in, const int* in_sizes, int n_in,
                              void* d_out, int out_size, void* d_ws, size_t ws_size,
                              hipStream_t stream) {
    const float* x  = (const float*)d_in[0];
    const int*   ei = (const int*)d_in[1];
    // d_in[2] = edge_attr, unused by GCNConv
    const float* W1 = (const float*)d_in[3];
    const float* b1 = (const float*)d_in[4];
    const float* W2 = (const float*)d_in[5];
    const float* b2 = (const float*)d_in[6];
    float* out = (float*)d_out;

    const int* src = ei;
    const int* dst = ei + N_EDGES;

    char* ws = (char*)d_ws;
    size_t npad = ((size_t)N_NODES * 4 + 255) / 256 * 256;
    float* dinv = (float*)ws;
    int*   off  = (int*)(ws + npad);
    int*   endp = (int*)(ws + 2 * npad);
    int*   bh   = (int*)(ws + 3 * npad);              // NVAL=50176 ints (~200 KB)
    int*   csr  = (int*)(ws + 3 * npad + 204800);
    unsigned* bkt = (unsigned*)((char*)csr + (size_t)N_EDGES * 4);
    unsigned short* y1h = (unsigned short*)((char*)bkt + (size_t)N_EDGES * 4);  // N*64 bf16
    unsigned short* y2h = (unsigned short*)((char*)y1h + (size_t)N_NODES * HID_F * 2);  // N*32 bf16 (y1h still live)

    dim3 blk(256);
    bucketA_kernel  <<<dim3(NBLK), blk, 0, stream>>>(dst, bh);
    scan_hist_kernel<<<dim3(1), dim3(1024), 0, stream>>>(bh);
    bucketB_kernel  <<<dim3(NBLK), blk, 0, stream>>>(src, dst, bh, bkt);
    sort_bucket_kernel<<<dim3(NBKT), blk, 0, stream>>>(bh, bkt, csr, off, endp, dinv);
    xw1_kernel      <<<dim3((N_NODES + XBM - 1) / XBM), blk, 0, stream>>>(x, W1, dinv, y1h);
    gather1_fused_kernel<<<dim3(N_NODES * 32 / 256), blk, 0, stream>>>(off, endp, csr, y1h, dinv, W2, b1, y2h);
    gather2_kernel  <<<dim3((N_NODES * 32 + 255) / 256), blk, 0, stream>>>(off, endp, csr, y2h, dinv, b2, out);
}